// Round 14
// baseline (117.527 us; speedup 1.0000x reference)
//
#include <hip/hip_runtime.h>
#include <math.h>

// Problem constants (fixed by the reference)
#define NQ      16384      // B*S = 8*2048
#define NSLOTS  8192
#define D       64
#define K       8

#define WV_ELEMS  (NQ * K * D)     // 8,388,608
#define IDX_OFF   (WV_ELEMS)
#define TSO_OFF   (IDX_OFF + NQ * K)

// ---------------- MFMA split path (P = prefilter, R = rescore) ----------------
#define QPB_P   32         // queries per P block
#define BLOCK_P 512        // 8 waves
#define HALVES  2          // slot halves -> grid 1024 -> 4 blocks/CU
#define SPW_P   (NSLOTS / HALVES / 8)   // 512 slots per wave
#define ITERS_P (SPW_P / 32)            // 16

#define QPB_R   8          // queries per R block -> grid 2048 (100% wave capacity)
#define BLOCK_R 256

// ws layout (unsigned short base):
//   [0, 524288)          kb    bf16 keys    [8192][64]
//   [524288, 1572864)    qb    bf16 q*0.125 [16384][64]
//   [1572864, 2097152)   pool  ushort[16384][32] PAIR-winner slot ids (16/half)
#define POOL_SHORT_OFF 1572864
#define WS_NEED_NEW  (4u * 1024u * 1024u)
#define WS_NEED_OLD  (3u * 1024u * 1024u)

using short8   = __attribute__((ext_vector_type(8))) short;
using ushort8  = __attribute__((ext_vector_type(8))) unsigned short;
using bf16x8   = __attribute__((ext_vector_type(8))) __bf16;
using f32x4    = __attribute__((ext_vector_type(4))) float;

#define MFMA_BF16(A, B, C) __builtin_amdgcn_mfma_f32_16x16x32_bf16((A), (B), (C), 0, 0, 0)

__device__ __forceinline__ bf16x8 load_frag(const unsigned short* p) {
    short8 s = *reinterpret_cast<const short8*>(p);
    return __builtin_bit_cast(bf16x8, s);
}

// Pack score into a float key: clear low 13 mantissa bits, OR in (8191 - slot).
__device__ __forceinline__ float packkey(float s, int code) {
    unsigned u = __float_as_uint(s) & 0xFFFFE000u;
    return __uint_as_float(u | (unsigned)code);
}

// Branchless insert into ascending sorted tv[0..7] (tv[0] = current 8th best).
__device__ __forceinline__ void ins8(float (&tv)[8], float key) {
    float k2 = fmaxf(key, tv[0]);
    float o0 = fminf(tv[1], k2);
    float o1 = __builtin_amdgcn_fmed3f(tv[1], tv[2], k2);
    float o2 = __builtin_amdgcn_fmed3f(tv[2], tv[3], k2);
    float o3 = __builtin_amdgcn_fmed3f(tv[3], tv[4], k2);
    float o4 = __builtin_amdgcn_fmed3f(tv[4], tv[5], k2);
    float o5 = __builtin_amdgcn_fmed3f(tv[5], tv[6], k2);
    float o6 = __builtin_amdgcn_fmed3f(tv[6], tv[7], k2);
    float o7 = fmaxf(tv[7], k2);
    tv[0]=o0; tv[1]=o1; tv[2]=o2; tv[3]=o3; tv[4]=o4; tv[5]=o5; tv[6]=o6; tv[7]=o7;
}

__device__ __forceinline__ void cs(float& a, float& b) {
    const float lo = fminf(a, b), hi = fmaxf(a, b);
    a = lo; b = hi;
}
// Sort an 8-element BITONIC sequence ascending (3-stage bitonic merge).
__device__ __forceinline__ void sort_bitonic8(float (&v)[8]) {
    cs(v[0],v[4]); cs(v[1],v[5]); cs(v[2],v[6]); cs(v[3],v[7]);
    cs(v[0],v[2]); cs(v[1],v[3]); cs(v[4],v[6]); cs(v[5],v[7]);
    cs(v[0],v[1]); cs(v[2],v[3]); cs(v[4],v[5]); cs(v[6],v[7]);
}

__device__ __forceinline__ void csu(unsigned long long& a, unsigned long long& b) {
    const bool lt = a < b;
    const unsigned long long lo = lt ? a : b;
    const unsigned long long hi = lt ? b : a;
    a = lo; b = hi;
}
__device__ __forceinline__ void sort_bitonic8_u64(unsigned long long (&v)[8]) {
    csu(v[0],v[4]); csu(v[1],v[5]); csu(v[2],v[6]); csu(v[3],v[7]);
    csu(v[0],v[2]); csu(v[1],v[3]); csu(v[4],v[6]); csu(v[5],v[7]);
    csu(v[0],v[1]); csu(v[2],v[3]); csu(v[4],v[5]); csu(v[6],v[7]);
}
// Full Batcher odd-even sort of 8 arbitrary u64 (19 comparators), ascending.
__device__ __forceinline__ void sort8_u64(unsigned long long (&v)[8]) {
    csu(v[0],v[1]); csu(v[2],v[3]); csu(v[4],v[5]); csu(v[6],v[7]);
    csu(v[0],v[2]); csu(v[1],v[3]); csu(v[4],v[6]); csu(v[5],v[7]);
    csu(v[1],v[2]); csu(v[5],v[6]);
    csu(v[0],v[4]); csu(v[1],v[5]); csu(v[2],v[6]); csu(v[3],v[7]);
    csu(v[2],v[4]); csu(v[3],v[5]);
    csu(v[1],v[2]); csu(v[3],v[4]); csu(v[5],v[6]);
}

// fp32 -> bf16 round-to-nearest-even (inputs are finite)
__device__ __forceinline__ unsigned short f2bf(float f) {
    unsigned u = __float_as_uint(f);
    return (unsigned short)((u + 0x7FFFu + ((u >> 16) & 1u)) >> 16);
}

__global__ __launch_bounds__(256)
void conv_kernel(const float* __restrict__ q, const float* __restrict__ k,
                 unsigned short* __restrict__ ws) {
    const int t = blockIdx.x * blockDim.x + threadIdx.x;
    if (t < 262144) {                      // queries: 1,048,576 floats = 262,144 float4
        float4 v = reinterpret_cast<const float4*>(q)[t];
        unsigned long long r =
              (unsigned long long)f2bf(v.x * 0.125f)
            | ((unsigned long long)f2bf(v.y * 0.125f) << 16)
            | ((unsigned long long)f2bf(v.z * 0.125f) << 32)
            | ((unsigned long long)f2bf(v.w * 0.125f) << 48);
        reinterpret_cast<unsigned long long*>(ws + 524288)[t] = r;   // Qb at +1MB
    } else if (t < 393216) {               // keys: 524,288 floats = 131,072 float4
        const int i = t - 262144;
        float4 v = reinterpret_cast<const float4*>(k)[i];
        unsigned long long r =
              (unsigned long long)f2bf(v.x)
            | ((unsigned long long)f2bf(v.y) << 16)
            | ((unsigned long long)f2bf(v.z) << 32)
            | ((unsigned long long)f2bf(v.w) << 48);
        reinterpret_cast<unsigned long long*>(ws)[i] = r;            // Kb at 0
    }
}

// ================= Kernel P: bf16 MFMA prefilter, PAIR-max selection ========
// Each adjacent slot pair contributes one packed key (fmax of the two).
// Lists/merges operate on pair-keys; pool = top-16 pair-winners per half.
// R rescans BOTH members of each winning pair (64 candidates/query, exact).
__global__ __launch_bounds__(BLOCK_P, 8)
void ltm_prefilter_kernel(const unsigned short* __restrict__ kb,
                          const unsigned short* __restrict__ qb,
                          unsigned short* __restrict__ poolu)
{
    __shared__ float candk[QPB_P][68];   // 64 packed pair-keys per query (+pad)

    const int tid  = threadIdx.x;
    const int lane = tid & 63;
    const int w    = tid >> 6;          // wave 0..7
    const int row  = lane & 15;
    const int g    = lane >> 4;         // 0..3
    const int g4   = g * 4;
    const int koff = g * 8;             // k-offset (elements) within 32-chunk
    const int bid  = blockIdx.x;
    const int qbase = (bid >> 1) * QPB_P;
    const int half  = bid & 1;

    // B fragments (queries), hoisted: 2 query subtiles x 2 k-chunks
    const unsigned short* qpA = qb + (size_t)(qbase + row) * D + koff;
    const bf16x8 bA0 = load_frag(qpA);
    const bf16x8 bA1 = load_frag(qpA + 32);
    const bf16x8 bB0 = load_frag(qpA + 16 * D);
    const bf16x8 bB1 = load_frag(qpA + 16 * D + 32);

    float tvA[8], tvB[8];
    #pragma unroll
    for (int i = 0; i < 8; ++i) { tvA[i] = -INFINITY; tvB[i] = -INFINITY; }

    const int wbase = half * (NSLOTS / HALVES) + w * SPW_P;

    // register prefetch (depth 1) + unroll 2
    const unsigned short* kp0 = kb + (size_t)(wbase + row) * D + koff;
    bf16x8 a00 = load_frag(kp0);
    bf16x8 a01 = load_frag(kp0 + 32);
    bf16x8 a10 = load_frag(kp0 + 16 * D);
    bf16x8 a11 = load_frag(kp0 + 16 * D + 32);

    int codeA = 8191 - (wbase + g4);   // complement base; decremented 32/iter

    #pragma unroll 2
    for (int it = 0; it < ITERS_P; ++it) {
        // prefetch next iter's A fragments (last iter reads past this wave's
        // range into kb/qb: valid ws memory, values unused)
        const int snext = wbase + (it + 1) * 32;
        const unsigned short* np_ = kb + (size_t)(snext + row) * D + koff;
        bf16x8 n00 = load_frag(np_);
        bf16x8 n01 = load_frag(np_ + 32);
        bf16x8 n10 = load_frag(np_ + 16 * D);
        bf16x8 n11 = load_frag(np_ + 16 * D + 32);

        const f32x4 z = {0.f, 0.f, 0.f, 0.f};
        f32x4 c00 = MFMA_BF16(a00, bA0, z);  c00 = MFMA_BF16(a01, bA1, c00);
        f32x4 c01 = MFMA_BF16(a00, bB0, z);  c01 = MFMA_BF16(a01, bB1, c01);
        f32x4 c10 = MFMA_BF16(a10, bA0, z);  c10 = MFMA_BF16(a11, bA1, c10);
        f32x4 c11 = MFMA_BF16(a10, bB0, z);  c11 = MFMA_BF16(a11, bB1, c11);

        // slot(tile0, r) = s0 + g4 + r ; slot(tile1, r) = s0 + 16 + g4 + r.
        // Pairs are slot-aligned (g4 even): {r=0,1} and {r=2,3}.
        // fmax of packed keys picks the better member, carrying its id.
        ins8(tvA, fmaxf(packkey(c00[0], codeA     ), packkey(c00[1], codeA -  1)));
        ins8(tvA, fmaxf(packkey(c00[2], codeA -  2), packkey(c00[3], codeA -  3)));
        ins8(tvA, fmaxf(packkey(c10[0], codeA - 16), packkey(c10[1], codeA - 17)));
        ins8(tvA, fmaxf(packkey(c10[2], codeA - 18), packkey(c10[3], codeA - 19)));
        ins8(tvB, fmaxf(packkey(c01[0], codeA     ), packkey(c01[1], codeA -  1)));
        ins8(tvB, fmaxf(packkey(c01[2], codeA -  2), packkey(c01[3], codeA -  3)));
        ins8(tvB, fmaxf(packkey(c11[0], codeA - 16), packkey(c11[1], codeA - 17)));
        ins8(tvB, fmaxf(packkey(c11[2], codeA - 18), packkey(c11[3], codeA - 19)));

        codeA -= 32;
        a00 = n00; a01 = n01; a10 = n10; a11 = n11;
    }

    // ---- In-wave merge to per-wave sorted top-8 pair-keys per query ----
    {
        float sA[8], sB[8];
        #pragma unroll
        for (int j = 0; j < 8; ++j) {
            sA[j] = __shfl_xor(tvA[j], 32, 64);
            sB[j] = __shfl_xor(tvB[j], 32, 64);
        }
        float mA[8], mB[8];
        #pragma unroll
        for (int j = 0; j < 8; ++j) {
            mA[j] = fmaxf(tvA[j], sA[7 - j]);
            mB[j] = fmaxf(tvB[j], sB[7 - j]);
        }
        sort_bitonic8(mA);
        sort_bitonic8(mB);
        #pragma unroll
        for (int j = 0; j < 8; ++j) {
            sA[j] = __shfl_xor(mA[j], 16, 64);
            sB[j] = __shfl_xor(mB[j], 16, 64);
        }
        float fA[8], fB[8];
        #pragma unroll
        for (int j = 0; j < 8; ++j) {
            fA[j] = fmaxf(mA[j], sA[7 - j]);
            fB[j] = fmaxf(mB[j], sB[7 - j]);
        }
        sort_bitonic8(fA);
        sort_bitonic8(fB);
        if (g == 0) {
            #pragma unroll
            for (int j = 0; j < 8; ++j) {
                candk[row     ][w * 8 + j] = fA[j];
                candk[row + 16][w * 8 + j] = fB[j];
            }
        }
    }
    __syncthreads();

    // ---- Block merge: 8 sorted-8 lists -> per-(query,half) sorted TOP-16.
    if (tid < 256) {
        const int  ql = tid >> 3;    // 0..31
        const int  jj = tid & 7;     // 0..7
        const bool hi = (jj & 1) != 0;

        float v[8];
        #pragma unroll
        for (int i = 0; i < 8; ++i) v[i] = candk[ql][jj * 8 + i];

        // Round 1 (xor 1): Batcher half-cleaner -> pair holds sorted-16.
        {
            float sk[8], mk[8];
            #pragma unroll
            for (int i = 0; i < 8; ++i) sk[i] = __shfl_xor(v[i], 1, 64);
            #pragma unroll
            for (int i = 0; i < 8; ++i)
                mk[i] = hi ? fmaxf(v[i], sk[7 - i]) : fminf(v[i], sk[7 - i]);
            sort_bitonic8(mk);
            #pragma unroll
            for (int i = 0; i < 8; ++i) v[i] = mk[i];
        }
        // Rounds 2 and 3 (xor 3, xor 5): top-16 of two sorted-16s.
        #pragma unroll
        for (int rnd = 0; rnd < 2; ++rnd) {
            const int st = rnd ? 5 : 3;
            float sk[8], mk[8], sk2[8];
            #pragma unroll
            for (int i = 0; i < 8; ++i) sk[i] = __shfl_xor(v[i], st, 64);
            #pragma unroll
            for (int i = 0; i < 8; ++i) mk[i] = fmaxf(v[i], sk[7 - i]);
            #pragma unroll
            for (int i = 0; i < 8; ++i) sk2[i] = __shfl_xor(mk[i], 1, 64);
            #pragma unroll
            for (int i = 0; i < 8; ++i)
                mk[i] = hi ? fmaxf(mk[i], sk2[i]) : fminf(mk[i], sk2[i]);
            sort_bitonic8(mk);
            #pragma unroll
            for (int i = 0; i < 8; ++i) v[i] = mk[i];
        }
        // Threads 0,1 hold the half's sorted top-16 pair-winners; write ids.
        if (jj < 2) {
            ushort8 o;
            #pragma unroll
            for (int i = 0; i < 8; ++i)
                o[i] = (unsigned short)(8191u - (__float_as_uint(v[i]) & 8191u));
            *reinterpret_cast<ushort8*>(
                poolu + ((size_t)(qbase + ql) * 32 + half * 16 + jj * 8)) = o;
        }
    }
}

// ================= Kernel R: exact fp32 rescore of 64 candidates/query =======
// 32 lanes per query (grid 2048 = 100% wave capacity). Each 4-lane subgroup
// owns 4 pool entries -> 8 slots (both pair members); full Batcher sort8 of
// exact u64 keys, then 3 merge rounds (strides 4, 8, 16) -> exact top-8.
__global__ __launch_bounds__(BLOCK_R, 8)
void ltm_rescore_kernel(const float* __restrict__ queries,
                        const float* __restrict__ keys_mem,
                        const float* __restrict__ vals_mem,
                        const float* __restrict__ fast_vals,
                        const float* __restrict__ timestamps,
                        const unsigned short* __restrict__ poolu,
                        float* __restrict__ out)
{
    const int tid = threadIdx.x;
    const int ql  = tid >> 5;    // 0..7
    const int l32 = tid & 31;
    const int sg  = l32 >> 2;    // 0..7
    const int ls4 = l32 & 3;     // 0..3
    const int q   = blockIdx.x * QPB_R + ql;

    float4 qv4[4];
    {
        const float4* qp = reinterpret_cast<const float4*>(queries) + (size_t)q * 16 + ls4 * 4;
        #pragma unroll
        for (int i = 0; i < 4; ++i) qv4[i] = qp[i];
    }

    unsigned long long tk[8];
    #pragma unroll
    for (int jt = 0; jt < 4; ++jt) {
        const int pe   = poolu[(size_t)q * 32 + sg * 4 + jt];   // pair winner id
        const int base = pe & ~1;                               // pair base slot
        #pragma unroll
        for (int hh = 0; hh < 2; ++hh) {
            const int sid = base + hh;
            const float4* kp = reinterpret_cast<const float4*>(keys_mem) + (size_t)sid * 16 + ls4 * 4;
            float p = 0.f;
            #pragma unroll
            for (int i = 0; i < 4; ++i) {
                const float4 kc = kp[i];
                p = fmaf(qv4[i].x, kc.x, p);
                p = fmaf(qv4[i].y, kc.y, p);
                p = fmaf(qv4[i].z, kc.z, p);
                p = fmaf(qv4[i].w, kc.w, p);
            }
            p += __shfl_xor(p, 1, 64);
            p += __shfl_xor(p, 2, 64);
            const float s = p * 0.125f;
            // exact total-order key: (orderable(score) << 13) | (8191 - sid)
            const unsigned u  = __float_as_uint(s);
            const unsigned ou = (u & 0x80000000u) ? ~u : (u | 0x80000000u);
            tk[jt * 2 + hh] = ((unsigned long long)ou << 13) | (unsigned)(8191 - sid);
        }
    }
    sort8_u64(tk);

    // Cross-subgroup merge: strides 4, 8, 16 (Batcher upper-half + bitonic sort).
    #pragma unroll
    for (int st = 4; st <= 16; st <<= 1) {
        unsigned long long sk[8], mk[8];
        #pragma unroll
        for (int j = 0; j < 8; ++j) sk[j] = __shfl_xor(tk[j], st, 64);
        #pragma unroll
        for (int j = 0; j < 8; ++j) {
            const unsigned long long a = tk[j], b = sk[7 - j];
            mk[j] = a > b ? a : b;
        }
        sort_bitonic8_u64(mk);
        #pragma unroll
        for (int j = 0; j < 8; ++j) tk[j] = mk[j];
    }

    // ---- decode + softmax (redundant per lane, no sync needed) ----
    float wv[K]; int wi[K];
    #pragma unroll
    for (int r = 0; r < K; ++r) {
        const unsigned long long best = tk[7 - r];
        const int      sid = 8191 - (int)(best & 8191ull);
        const unsigned ou  = (unsigned)(best >> 13);
        const unsigned ub  = (ou & 0x80000000u) ? (ou & 0x7FFFFFFFu) : ~ou;
        wv[r] = __uint_as_float(ub);
        wi[r] = sid;
    }
    const float m = wv[0];
    float e[K]; float sum = 0.f;
    #pragma unroll
    for (int r = 0; r < K; ++r) { e[r] = expf(wv[r] - m); sum += e[r]; }
    const float inv = 1.f / sum;

    // ---- epilogue — lane (r, s4) = (l32>>2, l32&3) owns 64 B of rank r ----
    {
        const int   r   = l32 >> 2;
        const int   s4  = l32 & 3;
        const int   id  = wi[r];
        const float wgt = e[r] * inv;
        const float4* vp = reinterpret_cast<const float4*>(vals_mem)  + (size_t)id * 16 + s4 * 4;
        const float4* fp = reinterpret_cast<const float4*>(fast_vals) + (size_t)id * 16 + s4 * 4;
        float4* op = reinterpret_cast<float4*>(out) + ((size_t)(q * K + r)) * 16 + s4 * 4;
        #pragma unroll
        for (int i = 0; i < 4; ++i) {
            const float4 a = vp[i];
            const float4 b = fp[i];
            float4 c;
            c.x = (a.x + b.x) * wgt;
            c.y = (a.y + b.y) * wgt;
            c.z = (a.z + b.z) * wgt;
            c.w = (a.w + b.w) * wgt;
            op[i] = c;
        }
        if (l32 < 8) {
            out[IDX_OFF + (size_t)q * K + l32] = (float)wi[l32];
        } else if (l32 < 16) {
            const int r2 = l32 - 8;
            out[TSO_OFF + (size_t)q * K + r2] = timestamps[wi[r2]];
        }
    }
}

// ============ Mid fallback: round-8 single kernel (ws in [3MB,4MB)) =========
#define QPB    32
#define BLOCK  512
#define WAVES  8
#define SPW    (NSLOTS / WAVES)
#define ITERS  (SPW / 32)

__global__ __launch_bounds__(BLOCK, 4)
void ltm_mfma_kernel(const float* __restrict__ queries,
                     const float* __restrict__ keys_mem,
                     const float* __restrict__ vals_mem,
                     const float* __restrict__ fast_vals,
                     const float* __restrict__ timestamps,
                     const unsigned short* __restrict__ kb,
                     const unsigned short* __restrict__ qb,
                     float* __restrict__ out)
{
    __shared__ float candk[QPB][68];

    const int tid  = threadIdx.x;
    const int lane = tid & 63;
    const int w    = tid >> 6;
    const int row  = lane & 15;
    const int g    = lane >> 4;
    const int g4   = g * 4;
    const int koff = g * 8;
    const int qbase = blockIdx.x * QPB;

    const unsigned short* qpA = qb + (size_t)(qbase + row) * D + koff;
    const bf16x8 bA0 = load_frag(qpA);
    const bf16x8 bA1 = load_frag(qpA + 32);
    const bf16x8 bB0 = load_frag(qpA + 16 * D);
    const bf16x8 bB1 = load_frag(qpA + 16 * D + 32);

    float tvA[8], tvB[8];
    #pragma unroll
    for (int i = 0; i < 8; ++i) { tvA[i] = -INFINITY; tvB[i] = -INFINITY; }

    const int wbase = w * SPW;
    const unsigned short* kp0 = kb + (size_t)(wbase + row) * D + koff;
    bf16x8 a00 = load_frag(kp0);
    bf16x8 a01 = load_frag(kp0 + 32);
    bf16x8 a10 = load_frag(kp0 + 16 * D);
    bf16x8 a11 = load_frag(kp0 + 16 * D + 32);

    int codeA = 8191 - (wbase + g4);

    #pragma unroll 2
    for (int it = 0; it < ITERS; ++it) {
        const int snext = wbase + (it + 1) * 32;
        const unsigned short* np_ = kb + (size_t)(snext + row) * D + koff;
        bf16x8 n00 = load_frag(np_);
        bf16x8 n01 = load_frag(np_ + 32);
        bf16x8 n10 = load_frag(np_ + 16 * D);
        bf16x8 n11 = load_frag(np_ + 16 * D + 32);

        const f32x4 z = {0.f, 0.f, 0.f, 0.f};
        f32x4 c00 = MFMA_BF16(a00, bA0, z);  c00 = MFMA_BF16(a01, bA1, c00);
        f32x4 c01 = MFMA_BF16(a00, bB0, z);  c01 = MFMA_BF16(a01, bB1, c01);
        f32x4 c10 = MFMA_BF16(a10, bA0, z);  c10 = MFMA_BF16(a11, bA1, c10);
        f32x4 c11 = MFMA_BF16(a10, bB0, z);  c11 = MFMA_BF16(a11, bB1, c11);

        ins8(tvA, packkey(c00[0], codeA     ));
        ins8(tvA, packkey(c00[1], codeA -  1));
        ins8(tvA, packkey(c00[2], codeA -  2));
        ins8(tvA, packkey(c00[3], codeA -  3));
        ins8(tvA, packkey(c10[0], codeA - 16));
        ins8(tvA, packkey(c10[1], codeA - 17));
        ins8(tvA, packkey(c10[2], codeA - 18));
        ins8(tvA, packkey(c10[3], codeA - 19));
        ins8(tvB, packkey(c01[0], codeA     ));
        ins8(tvB, packkey(c01[1], codeA -  1));
        ins8(tvB, packkey(c01[2], codeA -  2));
        ins8(tvB, packkey(c01[3], codeA -  3));
        ins8(tvB, packkey(c11[0], codeA - 16));
        ins8(tvB, packkey(c11[1], codeA - 17));
        ins8(tvB, packkey(c11[2], codeA - 18));
        ins8(tvB, packkey(c11[3], codeA - 19));

        codeA -= 32;
        a00 = n00; a01 = n01; a10 = n10; a11 = n11;
    }

    {
        float sA[8], sB[8];
        #pragma unroll
        for (int j = 0; j < 8; ++j) {
            sA[j] = __shfl_xor(tvA[j], 32, 64);
            sB[j] = __shfl_xor(tvB[j], 32, 64);
        }
        float mA[8], mB[8];
        #pragma unroll
        for (int j = 0; j < 8; ++j) {
            mA[j] = fmaxf(tvA[j], sA[7 - j]);
            mB[j] = fmaxf(tvB[j], sB[7 - j]);
        }
        sort_bitonic8(mA);
        sort_bitonic8(mB);
        #pragma unroll
        for (int j = 0; j < 8; ++j) {
            sA[j] = __shfl_xor(mA[j], 16, 64);
            sB[j] = __shfl_xor(mB[j], 16, 64);
        }
        if (g == 0) {
            #pragma unroll
            for (int j = 0; j < 8; ++j) {
                candk[row     ][w * 8 + j] = fmaxf(mA[j], sA[7 - j]);
                candk[row + 16][w * 8 + j] = fmaxf(mB[j], sB[7 - j]);
            }
        }
    }
    __syncthreads();

    const int ql  = tid >> 4;
    const int l16 = tid & 15;
    const int sg  = l16 >> 2;
    const int ls4 = l16 & 3;
    const int q   = qbase + ql;

    float4 qv4[4];
    {
        const float4* qp = reinterpret_cast<const float4*>(queries) + (size_t)q * 16 + ls4 * 4;
        #pragma unroll
        for (int i = 0; i < 4; ++i) qv4[i] = qp[i];
    }

    unsigned long long tk[8];
    #pragma unroll
    for (int i = 0; i < 8; ++i) tk[i] = 0ull;

    #pragma unroll 4
    for (int jt = 0; jt < 16; ++jt) {
        const float fk  = candk[ql][sg * 16 + jt];
        const int   sid = 8191 - (int)(__float_as_uint(fk) & 8191u);
        const float4* kp = reinterpret_cast<const float4*>(keys_mem) + (size_t)sid * 16 + ls4 * 4;
        float p = 0.f;
        #pragma unroll
        for (int i = 0; i < 4; ++i) {
            const float4 kc = kp[i];
            p = fmaf(qv4[i].x, kc.x, p);
            p = fmaf(qv4[i].y, kc.y, p);
            p = fmaf(qv4[i].z, kc.z, p);
            p = fmaf(qv4[i].w, kc.w, p);
        }
        p += __shfl_xor(p, 1, 64);
        p += __shfl_xor(p, 2, 64);
        const float s = p * 0.125f;
        const unsigned u  = __float_as_uint(s);
        const unsigned ou = (u & 0x80000000u) ? ~u : (u | 0x80000000u);
        const unsigned long long key =
            ((unsigned long long)ou << 13) | (unsigned)(8191 - sid);
        if (key > tk[0]) {
            tk[0] = key;
            #pragma unroll
            for (int uu = 0; uu < 7; ++uu) {
                const bool sw = tk[uu] > tk[uu + 1];
                const unsigned long long x = sw ? tk[uu + 1] : tk[uu];
                const unsigned long long y = sw ? tk[uu]     : tk[uu + 1];
                tk[uu] = x; tk[uu + 1] = y;
            }
        }
    }

    #pragma unroll
    for (int st = 4; st <= 8; st <<= 1) {
        unsigned long long sk[8], mk[8];
        #pragma unroll
        for (int j = 0; j < 8; ++j) sk[j] = __shfl_xor(tk[j], st, 64);
        #pragma unroll
        for (int j = 0; j < 8; ++j) {
            const unsigned long long a = tk[j], b = sk[7 - j];
            mk[j] = a > b ? a : b;
        }
        sort_bitonic8_u64(mk);
        #pragma unroll
        for (int j = 0; j < 8; ++j) tk[j] = mk[j];
    }

    float wv[K]; int wi[K];
    #pragma unroll
    for (int r = 0; r < K; ++r) {
        const unsigned long long best = tk[7 - r];
        const int      sid = 8191 - (int)(best & 8191ull);
        const unsigned ou  = (unsigned)(best >> 13);
        const unsigned ub  = (ou & 0x80000000u) ? (ou & 0x7FFFFFFFu) : ~ou;
        wv[r] = __uint_as_float(ub);
        wi[r] = sid;
    }
    const float m = wv[0];
    float e[K]; float sum = 0.f;
    #pragma unroll
    for (int r = 0; r < K; ++r) { e[r] = expf(wv[r] - m); sum += e[r]; }
    const float inv = 1.f / sum;

    {
        const int   r   = l16 >> 1;
        const int   h   = l16 & 1;
        const int   id  = wi[r];
        const float wgt = e[r] * inv;
        const float4* vp = reinterpret_cast<const float4*>(vals_mem)  + (size_t)id * 16 + h * 8;
        const float4* fp = reinterpret_cast<const float4*>(fast_vals) + (size_t)id * 16 + h * 8;
        float4* op = reinterpret_cast<float4*>(out) + ((size_t)(q * K + r)) * 16 + h * 8;
        #pragma unroll
        for (int i = 0; i < 8; ++i) {
            const float4 a = vp[i];
            const float4 b = fp[i];
            float4 c;
            c.x = (a.x + b.x) * wgt;
            c.y = (a.y + b.y) * wgt;
            c.z = (a.z + b.z) * wgt;
            c.w = (a.w + b.w) * wgt;
            op[i] = c;
        }
        if (l16 < 8) {
            out[IDX_OFF + (size_t)q * K + l16] = (float)wi[l16];
        } else {
            const int r2 = l16 - 8;
            out[TSO_OFF + (size_t)q * K + r2] = timestamps[wi[r2]];
        }
    }
}

// ---------------- Last-resort fallback (pure fp32, ws < 3MB) ----------------
#define FQPB   32
#define FTPQ   8
#define FBLOCK 256
#define FTS    128
#define FLDK   68
#define FNTILES (NSLOTS / FTS)

__global__ __launch_bounds__(FBLOCK, 2)
void ltm_fused_kernel(const float* __restrict__ queries,
                      const float* __restrict__ keys_mem,
                      const float* __restrict__ vals_mem,
                      const float* __restrict__ fast_vals,
                      const float* __restrict__ timestamps,
                      float* __restrict__ out)
{
    __shared__ float kt[FTS * FLDK];
    __shared__ float candv[FQPB][FTPQ * K];
    __shared__ int   candi[FQPB][FTPQ * K];
    __shared__ float selw[FQPB][K];
    __shared__ int   seli[FQPB][K];

    const int tid = threadIdx.x;
    const int ql  = tid / FTPQ;
    const int sub = tid % FTPQ;
    const int q   = blockIdx.x * FQPB + ql;

    float4 qv[D / 4];
    {
        const float4* qp = reinterpret_cast<const float4*>(queries + (size_t)q * D);
        #pragma unroll
        for (int i = 0; i < D / 4; ++i) qv[i] = qp[i];
    }

    float tv[K]; int ti[K];
    #pragma unroll
    for (int i = 0; i < K; ++i) { tv[i] = -INFINITY; ti[i] = 0; }

    for (int tile = 0; tile < FNTILES; ++tile) {
        __syncthreads();
        {
            const float4* kg = reinterpret_cast<const float4*>(keys_mem + (size_t)tile * FTS * D);
            #pragma unroll
            for (int i = 0; i < (FTS * D / 4) / FBLOCK; ++i) {
                const int e = tid + i * FBLOCK;
                const int row = e >> 4;
                const int col = e & 15;
                *reinterpret_cast<float4*>(&kt[row * FLDK + col * 4]) = kg[e];
            }
        }
        __syncthreads();

        #pragma unroll 4
        for (int j = 0; j < FTS / FTPQ; ++j) {
            const int local = sub + j * FTPQ;
            const float* kr = &kt[local * FLDK];
            float4 a0 = make_float4(0.f, 0.f, 0.f, 0.f);
            float4 a1 = make_float4(0.f, 0.f, 0.f, 0.f);
            #pragma unroll
            for (int i = 0; i < D / 4; i += 2) {
                const float4 k0 = *reinterpret_cast<const float4*>(&kr[(i + 0) * 4]);
                const float4 k1 = *reinterpret_cast<const float4*>(&kr[(i + 1) * 4]);
                a0.x = fmaf(k0.x, qv[i].x, a0.x);   a0.y = fmaf(k0.y, qv[i].y, a0.y);
                a0.z = fmaf(k0.z, qv[i].z, a0.z);   a0.w = fmaf(k0.w, qv[i].w, a0.w);
                a1.x = fmaf(k1.x, qv[i+1].x, a1.x); a1.y = fmaf(k1.y, qv[i+1].y, a1.y);
                a1.z = fmaf(k1.z, qv[i+1].z, a1.z); a1.w = fmaf(k1.w, qv[i+1].w, a1.w);
            }
            float s = ((a0.x + a1.x) + (a0.y + a1.y)) + ((a0.z + a1.z) + (a0.w + a1.w));
            s *= 0.125f;
            const int gid = tile * FTS + local;
            if (s > tv[0]) {
                tv[0] = s; ti[0] = gid;
                #pragma unroll
                for (int u = 0; u < K - 1; ++u) {
                    const bool sw = tv[u] > tv[u + 1];
                    const float va = sw ? tv[u + 1] : tv[u];
                    const float vb = sw ? tv[u]     : tv[u + 1];
                    const int   ia = sw ? ti[u + 1] : ti[u];
                    const int   ib = sw ? ti[u]     : ti[u + 1];
                    tv[u] = va; tv[u + 1] = vb; ti[u] = ia; ti[u + 1] = ib;
                }
            }
        }
    }

    #pragma unroll
    for (int i = 0; i < K; ++i) {
        candv[ql][sub * K + i] = tv[i];
        candi[ql][sub * K + i] = ti[i];
    }
    __syncthreads();

    if (sub == 0) {
        float wv[K]; int wi[K];
        #pragma unroll
        for (int r = 0; r < K; ++r) {
            float bv = -INFINITY; int bi = 0x7fffffff; int bp = 0;
            for (int c = 0; c < FTPQ * K; ++c) {
                const float v = candv[ql][c];
                const int  id = candi[ql][c];
                if ((v > bv) || (v == bv && id < bi)) { bv = v; bi = id; bp = c; }
            }
            candv[ql][bp] = -INFINITY;
            wv[r] = bv; wi[r] = bi;
        }
        const float m = wv[0];
        float e[K]; float sum = 0.f;
        #pragma unroll
        for (int r = 0; r < K; ++r) { e[r] = expf(wv[r] - m); sum += e[r]; }
        const float inv = 1.f / sum;
        #pragma unroll
        for (int r = 0; r < K; ++r) { selw[ql][r] = e[r] * inv; seli[ql][r] = wi[r]; }
    }
    __syncthreads();

    {
        const int r = sub;
        const int id = seli[ql][r];
        const float w = selw[ql][r];
        const float4* vp = reinterpret_cast<const float4*>(vals_mem  + (size_t)id * D);
        const float4* fp = reinterpret_cast<const float4*>(fast_vals + (size_t)id * D);
        float4* op = reinterpret_cast<float4*>(out + (size_t)(q * K + r) * D);
        #pragma unroll
        for (int i = 0; i < D / 4; ++i) {
            const float4 a = vp[i];
            const float4 b = fp[i];
            float4 c;
            c.x = (a.x + b.x) * w; c.y = (a.y + b.y) * w;
            c.z = (a.z + b.z) * w; c.w = (a.w + b.w) * w;
            op[i] = c;
        }
        out[IDX_OFF + (size_t)q * K + r] = (float)id;
        out[TSO_OFF + (size_t)q * K + r] = timestamps[id];
    }
}

extern "C" void kernel_launch(void* const* d_in, const int* in_sizes, int n_in,
                              void* d_out, int out_size, void* d_ws, size_t ws_size,
                              hipStream_t stream) {
    (void)in_sizes; (void)n_in; (void)out_size;
    const float* queries    = (const float*)d_in[0];
    const float* keys_mem   = (const float*)d_in[1];
    const float* vals_mem   = (const float*)d_in[2];
    const float* fast_vals  = (const float*)d_in[3];
    const float* timestamps = (const float*)d_in[4];
    float* out = (float*)d_out;

    if (ws_size >= WS_NEED_NEW) {
        unsigned short* ws = (unsigned short*)d_ws;
        unsigned short* poolu = ws + POOL_SHORT_OFF;
        conv_kernel<<<1536, 256, 0, stream>>>(queries, keys_mem, ws);
        ltm_prefilter_kernel<<<(NQ / QPB_P) * HALVES, BLOCK_P, 0, stream>>>(
            ws /*Kb*/, ws + 524288 /*Qb*/, poolu);
        ltm_rescore_kernel<<<NQ / QPB_R, BLOCK_R, 0, stream>>>(
            queries, keys_mem, vals_mem, fast_vals, timestamps, poolu, out);
    } else if (ws_size >= WS_NEED_OLD) {
        unsigned short* ws = (unsigned short*)d_ws;
        conv_kernel<<<1536, 256, 0, stream>>>(queries, keys_mem, ws);
        ltm_mfma_kernel<<<NQ / QPB, BLOCK, 0, stream>>>(
            queries, keys_mem, vals_mem, fast_vals, timestamps,
            ws /*Kb*/, ws + 524288 /*Qb*/, out);
    } else {
        ltm_fused_kernel<<<NQ / FQPB, FBLOCK, 0, stream>>>(
            queries, keys_mem, vals_mem, fast_vals, timestamps, out);
    }
}

// Round 15
// 110.337 us; speedup vs baseline: 1.0652x; 1.0652x over previous
//
#include <hip/hip_runtime.h>
#include <math.h>

// Problem constants (fixed by the reference)
#define NQ      16384      // B*S = 8*2048
#define NSLOTS  8192
#define D       64
#define K       8

#define WV_ELEMS  (NQ * K * D)     // 8,388,608
#define IDX_OFF   (WV_ELEMS)
#define TSO_OFF   (IDX_OFF + NQ * K)

// ---------------- MFMA split path (P = prefilter, R = rescore) ----------------
#define QPB_P   32         // queries per P block
#define BLOCK_P 512        // 8 waves
#define HALVES  2          // slot halves -> grid 1024 -> 4 blocks/CU
#define SPW_P   (NSLOTS / HALVES / 8)   // 512 slots per wave
#define ITERS_P (SPW_P / 32)            // 16

#define QPB_R   8          // queries per R block -> grid 2048 (100% wave capacity)
#define BLOCK_R 256

// ws layout (unsigned short base):
//   [0, 524288)          kb    bf16 keys  [8192][64]
//   [524288, 1572864)    qb    (legacy region, used only by mid fallback)
//   [1572864, 2097152)   pool  ushort[16384][32] slot ids (16 per half)
#define POOL_SHORT_OFF 1572864
#define WS_NEED_NEW  (4u * 1024u * 1024u)
#define WS_NEED_OLD  (3u * 1024u * 1024u)

using short8   = __attribute__((ext_vector_type(8))) short;
using ushort8  = __attribute__((ext_vector_type(8))) unsigned short;
using bf16x8   = __attribute__((ext_vector_type(8))) __bf16;
using f32x4    = __attribute__((ext_vector_type(4))) float;

#define MFMA_BF16(A, B, C) __builtin_amdgcn_mfma_f32_16x16x32_bf16((A), (B), (C), 0, 0, 0)

__device__ __forceinline__ bf16x8 load_frag(const unsigned short* p) {
    short8 s = *reinterpret_cast<const short8*>(p);
    return __builtin_bit_cast(bf16x8, s);
}

// Pack score into a float key: clear low 13 mantissa bits, OR in (8191 - slot).
__device__ __forceinline__ float packkey(float s, int code) {
    unsigned u = __float_as_uint(s) & 0xFFFFE000u;
    return __uint_as_float(u | (unsigned)code);
}

// Branchless insert into ascending sorted tv[0..7] (tv[0] = current 8th best).
__device__ __forceinline__ void ins8(float (&tv)[8], float key) {
    float k2 = fmaxf(key, tv[0]);
    float o0 = fminf(tv[1], k2);
    float o1 = __builtin_amdgcn_fmed3f(tv[1], tv[2], k2);
    float o2 = __builtin_amdgcn_fmed3f(tv[2], tv[3], k2);
    float o3 = __builtin_amdgcn_fmed3f(tv[3], tv[4], k2);
    float o4 = __builtin_amdgcn_fmed3f(tv[4], tv[5], k2);
    float o5 = __builtin_amdgcn_fmed3f(tv[5], tv[6], k2);
    float o6 = __builtin_amdgcn_fmed3f(tv[6], tv[7], k2);
    float o7 = fmaxf(tv[7], k2);
    tv[0]=o0; tv[1]=o1; tv[2]=o2; tv[3]=o3; tv[4]=o4; tv[5]=o5; tv[6]=o6; tv[7]=o7;
}

__device__ __forceinline__ void cs(float& a, float& b) {
    const float lo = fminf(a, b), hi = fmaxf(a, b);
    a = lo; b = hi;
}
// Sort an 8-element BITONIC sequence ascending (3-stage bitonic merge).
__device__ __forceinline__ void sort_bitonic8(float (&v)[8]) {
    cs(v[0],v[4]); cs(v[1],v[5]); cs(v[2],v[6]); cs(v[3],v[7]);
    cs(v[0],v[2]); cs(v[1],v[3]); cs(v[4],v[6]); cs(v[5],v[7]);
    cs(v[0],v[1]); cs(v[2],v[3]); cs(v[4],v[5]); cs(v[6],v[7]);
}

__device__ __forceinline__ void csu(unsigned long long& a, unsigned long long& b) {
    const bool lt = a < b;
    const unsigned long long lo = lt ? a : b;
    const unsigned long long hi = lt ? b : a;
    a = lo; b = hi;
}
__device__ __forceinline__ void sort_bitonic8_u64(unsigned long long (&v)[8]) {
    csu(v[0],v[4]); csu(v[1],v[5]); csu(v[2],v[6]); csu(v[3],v[7]);
    csu(v[0],v[2]); csu(v[1],v[3]); csu(v[4],v[6]); csu(v[5],v[7]);
    csu(v[0],v[1]); csu(v[2],v[3]); csu(v[4],v[5]); csu(v[6],v[7]);
}

// fp32 -> bf16 round-to-nearest-even (inputs are finite)
__device__ __forceinline__ unsigned short f2bf(float f) {
    unsigned u = __float_as_uint(f);
    return (unsigned short)((u + 0x7FFFu + ((u >> 16) & 1u)) >> 16);
}

// Convert 8 consecutive fp32 to a bf16x8 fragment (RNE). Scale is irrelevant
// for prefilter ranking (x0.125 is an exact exponent shift), so none applied.
__device__ __forceinline__ bf16x8 cvt8(const float* p) {
    const float4 v0 = *reinterpret_cast<const float4*>(p);
    const float4 v1 = *reinterpret_cast<const float4*>(p + 4);
    ushort8 r;
    r[0] = f2bf(v0.x); r[1] = f2bf(v0.y); r[2] = f2bf(v0.z); r[3] = f2bf(v0.w);
    r[4] = f2bf(v1.x); r[5] = f2bf(v1.y); r[6] = f2bf(v1.z); r[7] = f2bf(v1.w);
    return __builtin_bit_cast(bf16x8, r);
}

// Keys-only conversion: 524,288 floats = 131,072 float4; one per thread.
__global__ __launch_bounds__(256)
void conv_keys_kernel(const float* __restrict__ k, unsigned short* __restrict__ kb) {
    const int t = blockIdx.x * blockDim.x + threadIdx.x;
    float4 v = reinterpret_cast<const float4*>(k)[t];
    unsigned long long r =
          (unsigned long long)f2bf(v.x)
        | ((unsigned long long)f2bf(v.y) << 16)
        | ((unsigned long long)f2bf(v.z) << 32)
        | ((unsigned long long)f2bf(v.w) << 48);
    reinterpret_cast<unsigned long long*>(kb)[t] = r;
}

// Legacy conv (queries+keys) — used only by the mid fallback path.
__global__ __launch_bounds__(256)
void conv_kernel(const float* __restrict__ q, const float* __restrict__ k,
                 unsigned short* __restrict__ ws) {
    const int t = blockIdx.x * blockDim.x + threadIdx.x;
    if (t < 262144) {
        float4 v = reinterpret_cast<const float4*>(q)[t];
        unsigned long long r =
              (unsigned long long)f2bf(v.x * 0.125f)
            | ((unsigned long long)f2bf(v.y * 0.125f) << 16)
            | ((unsigned long long)f2bf(v.z * 0.125f) << 32)
            | ((unsigned long long)f2bf(v.w * 0.125f) << 48);
        reinterpret_cast<unsigned long long*>(ws + 524288)[t] = r;
    } else if (t < 393216) {
        const int i = t - 262144;
        float4 v = reinterpret_cast<const float4*>(k)[i];
        unsigned long long r =
              (unsigned long long)f2bf(v.x)
            | ((unsigned long long)f2bf(v.y) << 16)
            | ((unsigned long long)f2bf(v.z) << 32)
            | ((unsigned long long)f2bf(v.w) << 48);
        reinterpret_cast<unsigned long long*>(ws)[i] = r;
    }
}

// ================= Kernel P: bf16 MFMA prefilter -> per-(query,half) top-16 =
// Round-13 structure; query fragments converted from fp32 on the fly.
__global__ __launch_bounds__(BLOCK_P, 8)
void ltm_prefilter_kernel(const unsigned short* __restrict__ kb,
                          const float* __restrict__ queries,
                          unsigned short* __restrict__ poolu)
{
    __shared__ float candk[QPB_P][68];   // 64 packed keys per query (+pad)

    const int tid  = threadIdx.x;
    const int lane = tid & 63;
    const int w    = tid >> 6;          // wave 0..7
    const int row  = lane & 15;
    const int g    = lane >> 4;         // 0..3
    const int g4   = g * 4;
    const int koff = g * 8;             // k-offset (elements) within 32-chunk
    const int bid  = blockIdx.x;
    const int qbase = (bid >> 1) * QPB_P;
    const int half  = bid & 1;

    // B fragments (queries), converted inline: 2 query subtiles x 2 k-chunks
    const float* qpA = queries + (size_t)(qbase + row) * D + koff;
    const bf16x8 bA0 = cvt8(qpA);
    const bf16x8 bA1 = cvt8(qpA + 32);
    const bf16x8 bB0 = cvt8(qpA + 16 * D);
    const bf16x8 bB1 = cvt8(qpA + 16 * D + 32);

    float tvA[8], tvB[8];
    #pragma unroll
    for (int i = 0; i < 8; ++i) { tvA[i] = -INFINITY; tvB[i] = -INFINITY; }

    const int wbase = half * (NSLOTS / HALVES) + w * SPW_P;

    // register prefetch (depth 1) + unroll 2
    const unsigned short* kp0 = kb + (size_t)(wbase + row) * D + koff;
    bf16x8 a00 = load_frag(kp0);
    bf16x8 a01 = load_frag(kp0 + 32);
    bf16x8 a10 = load_frag(kp0 + 16 * D);
    bf16x8 a11 = load_frag(kp0 + 16 * D + 32);

    int codeA = 8191 - (wbase + g4);   // complement base; decremented 32/iter

    #pragma unroll 2
    for (int it = 0; it < ITERS_P; ++it) {
        // prefetch next iter's A fragments (last iter reads past this wave's
        // range: valid ws memory, values unused)
        const int snext = wbase + (it + 1) * 32;
        const unsigned short* np_ = kb + (size_t)(snext + row) * D + koff;
        bf16x8 n00 = load_frag(np_);
        bf16x8 n01 = load_frag(np_ + 32);
        bf16x8 n10 = load_frag(np_ + 16 * D);
        bf16x8 n11 = load_frag(np_ + 16 * D + 32);

        const f32x4 z = {0.f, 0.f, 0.f, 0.f};
        f32x4 c00 = MFMA_BF16(a00, bA0, z);  c00 = MFMA_BF16(a01, bA1, c00);
        f32x4 c01 = MFMA_BF16(a00, bB0, z);  c01 = MFMA_BF16(a01, bB1, c01);
        f32x4 c10 = MFMA_BF16(a10, bA0, z);  c10 = MFMA_BF16(a11, bA1, c10);
        f32x4 c11 = MFMA_BF16(a10, bB0, z);  c11 = MFMA_BF16(a11, bB1, c11);

        // slot(tile0, r) = s0 + g4 + r ; slot(tile1, r) = s0 + 16 + g4 + r
        ins8(tvA, packkey(c00[0], codeA     ));
        ins8(tvA, packkey(c00[1], codeA -  1));
        ins8(tvA, packkey(c00[2], codeA -  2));
        ins8(tvA, packkey(c00[3], codeA -  3));
        ins8(tvA, packkey(c10[0], codeA - 16));
        ins8(tvA, packkey(c10[1], codeA - 17));
        ins8(tvA, packkey(c10[2], codeA - 18));
        ins8(tvA, packkey(c10[3], codeA - 19));
        ins8(tvB, packkey(c01[0], codeA     ));
        ins8(tvB, packkey(c01[1], codeA -  1));
        ins8(tvB, packkey(c01[2], codeA -  2));
        ins8(tvB, packkey(c01[3], codeA -  3));
        ins8(tvB, packkey(c11[0], codeA - 16));
        ins8(tvB, packkey(c11[1], codeA - 17));
        ins8(tvB, packkey(c11[2], codeA - 18));
        ins8(tvB, packkey(c11[3], codeA - 19));

        codeA -= 32;
        a00 = n00; a01 = n01; a10 = n10; a11 = n11;
    }

    // ---- In-wave merge to per-wave sorted top-8 per query ----
    {
        float sA[8], sB[8];
        #pragma unroll
        for (int j = 0; j < 8; ++j) {
            sA[j] = __shfl_xor(tvA[j], 32, 64);
            sB[j] = __shfl_xor(tvB[j], 32, 64);
        }
        float mA[8], mB[8];
        #pragma unroll
        for (int j = 0; j < 8; ++j) {
            mA[j] = fmaxf(tvA[j], sA[7 - j]);
            mB[j] = fmaxf(tvB[j], sB[7 - j]);
        }
        sort_bitonic8(mA);
        sort_bitonic8(mB);
        #pragma unroll
        for (int j = 0; j < 8; ++j) {
            sA[j] = __shfl_xor(mA[j], 16, 64);
            sB[j] = __shfl_xor(mB[j], 16, 64);
        }
        float fA[8], fB[8];
        #pragma unroll
        for (int j = 0; j < 8; ++j) {
            fA[j] = fmaxf(mA[j], sA[7 - j]);
            fB[j] = fmaxf(mB[j], sB[7 - j]);
        }
        sort_bitonic8(fA);
        sort_bitonic8(fB);
        if (g == 0) {
            #pragma unroll
            for (int j = 0; j < 8; ++j) {
                candk[row     ][w * 8 + j] = fA[j];
                candk[row + 16][w * 8 + j] = fB[j];
            }
        }
    }
    __syncthreads();

    // ---- Block merge: 8 sorted-8 lists -> per-(query,half) sorted TOP-16.
    if (tid < 256) {
        const int  ql = tid >> 3;    // 0..31
        const int  jj = tid & 7;     // 0..7
        const bool hi = (jj & 1) != 0;

        float v[8];
        #pragma unroll
        for (int i = 0; i < 8; ++i) v[i] = candk[ql][jj * 8 + i];

        // Round 1 (xor 1): Batcher half-cleaner -> pair holds sorted-16.
        {
            float sk[8], mk[8];
            #pragma unroll
            for (int i = 0; i < 8; ++i) sk[i] = __shfl_xor(v[i], 1, 64);
            #pragma unroll
            for (int i = 0; i < 8; ++i)
                mk[i] = hi ? fmaxf(v[i], sk[7 - i]) : fminf(v[i], sk[7 - i]);
            sort_bitonic8(mk);
            #pragma unroll
            for (int i = 0; i < 8; ++i) v[i] = mk[i];
        }
        // Rounds 2 and 3 (xor 3, xor 5): top-16 of two sorted-16s.
        #pragma unroll
        for (int rnd = 0; rnd < 2; ++rnd) {
            const int st = rnd ? 5 : 3;
            float sk[8], mk[8], sk2[8];
            #pragma unroll
            for (int i = 0; i < 8; ++i) sk[i] = __shfl_xor(v[i], st, 64);
            #pragma unroll
            for (int i = 0; i < 8; ++i) mk[i] = fmaxf(v[i], sk[7 - i]);
            #pragma unroll
            for (int i = 0; i < 8; ++i) sk2[i] = __shfl_xor(mk[i], 1, 64);
            #pragma unroll
            for (int i = 0; i < 8; ++i)
                mk[i] = hi ? fmaxf(mk[i], sk2[i]) : fminf(mk[i], sk2[i]);
            sort_bitonic8(mk);
            #pragma unroll
            for (int i = 0; i < 8; ++i) v[i] = mk[i];
        }
        // Threads 0,1 hold the half's sorted top-16; write slot ids (ushort).
        if (jj < 2) {
            ushort8 o;
            #pragma unroll
            for (int i = 0; i < 8; ++i)
                o[i] = (unsigned short)(8191u - (__float_as_uint(v[i]) & 8191u));
            *reinterpret_cast<ushort8*>(
                poolu + ((size_t)(qbase + ql) * 32 + half * 16 + jj * 8)) = o;
        }
    }
}

// ================= Kernel R: exact fp32 rescore of 32 candidates/query =======
// 32 lanes per query (grid 2048 = 100% wave capacity). Each 4-lane subgroup
// owns 4 candidates; sorted-4 zero-padded into depth-8, then 3 Batcher merge
// rounds (strides 4, 8, 16) produce the exact top-8 on every lane.
__global__ __launch_bounds__(BLOCK_R, 8)
void ltm_rescore_kernel(const float* __restrict__ queries,
                        const float* __restrict__ keys_mem,
                        const float* __restrict__ vals_mem,
                        const float* __restrict__ fast_vals,
                        const float* __restrict__ timestamps,
                        const unsigned short* __restrict__ poolu,
                        float* __restrict__ out)
{
    const int tid = threadIdx.x;
    const int ql  = tid >> 5;    // 0..7
    const int l32 = tid & 31;
    const int sg  = l32 >> 2;    // 0..7
    const int ls4 = l32 & 3;     // 0..3
    const int q   = blockIdx.x * QPB_R + ql;

    float4 qv4[4];
    {
        const float4* qp = reinterpret_cast<const float4*>(queries) + (size_t)q * 16 + ls4 * 4;
        #pragma unroll
        for (int i = 0; i < 4; ++i) qv4[i] = qp[i];
    }

    unsigned long long kk[4];
    #pragma unroll
    for (int jt = 0; jt < 4; ++jt) {
        const int sid = poolu[(size_t)q * 32 + sg * 4 + jt];    // broadcast load
        const float4* kp = reinterpret_cast<const float4*>(keys_mem) + (size_t)sid * 16 + ls4 * 4;
        float p = 0.f;
        #pragma unroll
        for (int i = 0; i < 4; ++i) {
            const float4 kc = kp[i];
            p = fmaf(qv4[i].x, kc.x, p);
            p = fmaf(qv4[i].y, kc.y, p);
            p = fmaf(qv4[i].z, kc.z, p);
            p = fmaf(qv4[i].w, kc.w, p);
        }
        p += __shfl_xor(p, 1, 64);
        p += __shfl_xor(p, 2, 64);
        const float s = p * 0.125f;
        // exact total-order key: (orderable(score) << 13) | (8191 - sid)
        const unsigned u  = __float_as_uint(s);
        const unsigned ou = (u & 0x80000000u) ? ~u : (u | 0x80000000u);
        kk[jt] = ((unsigned long long)ou << 13) | (unsigned)(8191 - sid);
    }
    // sort-4 (5 comparators), then zero-pad into ascending depth-8 list
    csu(kk[0], kk[1]); csu(kk[2], kk[3]);
    csu(kk[0], kk[2]); csu(kk[1], kk[3]);
    csu(kk[1], kk[2]);
    unsigned long long tk[8];
    tk[0] = 0ull; tk[1] = 0ull; tk[2] = 0ull; tk[3] = 0ull;
    tk[4] = kk[0]; tk[5] = kk[1]; tk[6] = kk[2]; tk[7] = kk[3];

    // Cross-subgroup merge: strides 4, 8, 16 (Batcher upper-half + bitonic sort).
    #pragma unroll
    for (int st = 4; st <= 16; st <<= 1) {
        unsigned long long sk[8], mk[8];
        #pragma unroll
        for (int j = 0; j < 8; ++j) sk[j] = __shfl_xor(tk[j], st, 64);
        #pragma unroll
        for (int j = 0; j < 8; ++j) {
            const unsigned long long a = tk[j], b = sk[7 - j];
            mk[j] = a > b ? a : b;
        }
        sort_bitonic8_u64(mk);
        #pragma unroll
        for (int j = 0; j < 8; ++j) tk[j] = mk[j];
    }

    // ---- decode + softmax (redundant per lane, no sync needed) ----
    float wv[K]; int wi[K];
    #pragma unroll
    for (int r = 0; r < K; ++r) {
        const unsigned long long best = tk[7 - r];
        const int      sid = 8191 - (int)(best & 8191ull);
        const unsigned ou  = (unsigned)(best >> 13);
        const unsigned ub  = (ou & 0x80000000u) ? (ou & 0x7FFFFFFFu) : ~ou;
        wv[r] = __uint_as_float(ub);
        wi[r] = sid;
    }
    const float m = wv[0];
    float e[K]; float sum = 0.f;
    #pragma unroll
    for (int r = 0; r < K; ++r) { e[r] = expf(wv[r] - m); sum += e[r]; }
    const float inv = 1.f / sum;

    // ---- epilogue — lane (r, s4) = (l32>>2, l32&3) owns 64 B of rank r ----
    {
        const int   r   = l32 >> 2;
        const int   s4  = l32 & 3;
        const int   id  = wi[r];
        const float wgt = e[r] * inv;
        const float4* vp = reinterpret_cast<const float4*>(vals_mem)  + (size_t)id * 16 + s4 * 4;
        const float4* fp = reinterpret_cast<const float4*>(fast_vals) + (size_t)id * 16 + s4 * 4;
        float4* op = reinterpret_cast<float4*>(out) + ((size_t)(q * K + r)) * 16 + s4 * 4;
        #pragma unroll
        for (int i = 0; i < 4; ++i) {
            const float4 a = vp[i];
            const float4 b = fp[i];
            float4 c;
            c.x = (a.x + b.x) * wgt;
            c.y = (a.y + b.y) * wgt;
            c.z = (a.z + b.z) * wgt;
            c.w = (a.w + b.w) * wgt;
            op[i] = c;
        }
        if (l32 < 8) {
            out[IDX_OFF + (size_t)q * K + l32] = (float)wi[l32];
        } else if (l32 < 16) {
            const int r2 = l32 - 8;
            out[TSO_OFF + (size_t)q * K + r2] = timestamps[wi[r2]];
        }
    }
}

// ============ Mid fallback: round-8 single kernel (ws in [3MB,4MB)) =========
#define QPB    32
#define BLOCK  512
#define WAVES  8
#define SPW    (NSLOTS / WAVES)
#define ITERS  (SPW / 32)

__global__ __launch_bounds__(BLOCK, 4)
void ltm_mfma_kernel(const float* __restrict__ queries,
                     const float* __restrict__ keys_mem,
                     const float* __restrict__ vals_mem,
                     const float* __restrict__ fast_vals,
                     const float* __restrict__ timestamps,
                     const unsigned short* __restrict__ kb,
                     const unsigned short* __restrict__ qb,
                     float* __restrict__ out)
{
    __shared__ float candk[QPB][68];

    const int tid  = threadIdx.x;
    const int lane = tid & 63;
    const int w    = tid >> 6;
    const int row  = lane & 15;
    const int g    = lane >> 4;
    const int g4   = g * 4;
    const int koff = g * 8;
    const int qbase = blockIdx.x * QPB;

    const unsigned short* qpA = qb + (size_t)(qbase + row) * D + koff;
    const bf16x8 bA0 = load_frag(qpA);
    const bf16x8 bA1 = load_frag(qpA + 32);
    const bf16x8 bB0 = load_frag(qpA + 16 * D);
    const bf16x8 bB1 = load_frag(qpA + 16 * D + 32);

    float tvA[8], tvB[8];
    #pragma unroll
    for (int i = 0; i < 8; ++i) { tvA[i] = -INFINITY; tvB[i] = -INFINITY; }

    const int wbase = w * SPW;
    const unsigned short* kp0 = kb + (size_t)(wbase + row) * D + koff;
    bf16x8 a00 = load_frag(kp0);
    bf16x8 a01 = load_frag(kp0 + 32);
    bf16x8 a10 = load_frag(kp0 + 16 * D);
    bf16x8 a11 = load_frag(kp0 + 16 * D + 32);

    int codeA = 8191 - (wbase + g4);

    #pragma unroll 2
    for (int it = 0; it < ITERS; ++it) {
        const int snext = wbase + (it + 1) * 32;
        const unsigned short* np_ = kb + (size_t)(snext + row) * D + koff;
        bf16x8 n00 = load_frag(np_);
        bf16x8 n01 = load_frag(np_ + 32);
        bf16x8 n10 = load_frag(np_ + 16 * D);
        bf16x8 n11 = load_frag(np_ + 16 * D + 32);

        const f32x4 z = {0.f, 0.f, 0.f, 0.f};
        f32x4 c00 = MFMA_BF16(a00, bA0, z);  c00 = MFMA_BF16(a01, bA1, c00);
        f32x4 c01 = MFMA_BF16(a00, bB0, z);  c01 = MFMA_BF16(a01, bB1, c01);
        f32x4 c10 = MFMA_BF16(a10, bA0, z);  c10 = MFMA_BF16(a11, bA1, c10);
        f32x4 c11 = MFMA_BF16(a10, bB0, z);  c11 = MFMA_BF16(a11, bB1, c11);

        ins8(tvA, packkey(c00[0], codeA     ));
        ins8(tvA, packkey(c00[1], codeA -  1));
        ins8(tvA, packkey(c00[2], codeA -  2));
        ins8(tvA, packkey(c00[3], codeA -  3));
        ins8(tvA, packkey(c10[0], codeA - 16));
        ins8(tvA, packkey(c10[1], codeA - 17));
        ins8(tvA, packkey(c10[2], codeA - 18));
        ins8(tvA, packkey(c10[3], codeA - 19));
        ins8(tvB, packkey(c01[0], codeA     ));
        ins8(tvB, packkey(c01[1], codeA -  1));
        ins8(tvB, packkey(c01[2], codeA -  2));
        ins8(tvB, packkey(c01[3], codeA -  3));
        ins8(tvB, packkey(c11[0], codeA - 16));
        ins8(tvB, packkey(c11[1], codeA - 17));
        ins8(tvB, packkey(c11[2], codeA - 18));
        ins8(tvB, packkey(c11[3], codeA - 19));

        codeA -= 32;
        a00 = n00; a01 = n01; a10 = n10; a11 = n11;
    }

    {
        float sA[8], sB[8];
        #pragma unroll
        for (int j = 0; j < 8; ++j) {
            sA[j] = __shfl_xor(tvA[j], 32, 64);
            sB[j] = __shfl_xor(tvB[j], 32, 64);
        }
        float mA[8], mB[8];
        #pragma unroll
        for (int j = 0; j < 8; ++j) {
            mA[j] = fmaxf(tvA[j], sA[7 - j]);
            mB[j] = fmaxf(tvB[j], sB[7 - j]);
        }
        sort_bitonic8(mA);
        sort_bitonic8(mB);
        #pragma unroll
        for (int j = 0; j < 8; ++j) {
            sA[j] = __shfl_xor(mA[j], 16, 64);
            sB[j] = __shfl_xor(mB[j], 16, 64);
        }
        if (g == 0) {
            #pragma unroll
            for (int j = 0; j < 8; ++j) {
                candk[row     ][w * 8 + j] = fmaxf(mA[j], sA[7 - j]);
                candk[row + 16][w * 8 + j] = fmaxf(mB[j], sB[7 - j]);
            }
        }
    }
    __syncthreads();

    const int ql  = tid >> 4;
    const int l16 = tid & 15;
    const int sg  = l16 >> 2;
    const int ls4 = l16 & 3;
    const int q   = qbase + ql;

    float4 qv4[4];
    {
        const float4* qp = reinterpret_cast<const float4*>(queries) + (size_t)q * 16 + ls4 * 4;
        #pragma unroll
        for (int i = 0; i < 4; ++i) qv4[i] = qp[i];
    }

    unsigned long long tk[8];
    #pragma unroll
    for (int i = 0; i < 8; ++i) tk[i] = 0ull;

    #pragma unroll 4
    for (int jt = 0; jt < 16; ++jt) {
        const float fk  = candk[ql][sg * 16 + jt];
        const int   sid = 8191 - (int)(__float_as_uint(fk) & 8191u);
        const float4* kp = reinterpret_cast<const float4*>(keys_mem) + (size_t)sid * 16 + ls4 * 4;
        float p = 0.f;
        #pragma unroll
        for (int i = 0; i < 4; ++i) {
            const float4 kc = kp[i];
            p = fmaf(qv4[i].x, kc.x, p);
            p = fmaf(qv4[i].y, kc.y, p);
            p = fmaf(qv4[i].z, kc.z, p);
            p = fmaf(qv4[i].w, kc.w, p);
        }
        p += __shfl_xor(p, 1, 64);
        p += __shfl_xor(p, 2, 64);
        const float s = p * 0.125f;
        const unsigned u  = __float_as_uint(s);
        const unsigned ou = (u & 0x80000000u) ? ~u : (u | 0x80000000u);
        const unsigned long long key =
            ((unsigned long long)ou << 13) | (unsigned)(8191 - sid);
        if (key > tk[0]) {
            tk[0] = key;
            #pragma unroll
            for (int uu = 0; uu < 7; ++uu) {
                const bool sw = tk[uu] > tk[uu + 1];
                const unsigned long long x = sw ? tk[uu + 1] : tk[uu];
                const unsigned long long y = sw ? tk[uu]     : tk[uu + 1];
                tk[uu] = x; tk[uu + 1] = y;
            }
        }
    }

    #pragma unroll
    for (int st = 4; st <= 8; st <<= 1) {
        unsigned long long sk[8], mk[8];
        #pragma unroll
        for (int j = 0; j < 8; ++j) sk[j] = __shfl_xor(tk[j], st, 64);
        #pragma unroll
        for (int j = 0; j < 8; ++j) {
            const unsigned long long a = tk[j], b = sk[7 - j];
            mk[j] = a > b ? a : b;
        }
        sort_bitonic8_u64(mk);
        #pragma unroll
        for (int j = 0; j < 8; ++j) tk[j] = mk[j];
    }

    float wv[K]; int wi[K];
    #pragma unroll
    for (int r = 0; r < K; ++r) {
        const unsigned long long best = tk[7 - r];
        const int      sid = 8191 - (int)(best & 8191ull);
        const unsigned ou  = (unsigned)(best >> 13);
        const unsigned ub  = (ou & 0x80000000u) ? (ou & 0x7FFFFFFFu) : ~ou;
        wv[r] = __uint_as_float(ub);
        wi[r] = sid;
    }
    const float m = wv[0];
    float e[K]; float sum = 0.f;
    #pragma unroll
    for (int r = 0; r < K; ++r) { e[r] = expf(wv[r] - m); sum += e[r]; }
    const float inv = 1.f / sum;

    {
        const int   r   = l16 >> 1;
        const int   h   = l16 & 1;
        const int   id  = wi[r];
        const float wgt = e[r] * inv;
        const float4* vp = reinterpret_cast<const float4*>(vals_mem)  + (size_t)id * 16 + h * 8;
        const float4* fp = reinterpret_cast<const float4*>(fast_vals) + (size_t)id * 16 + h * 8;
        float4* op = reinterpret_cast<float4*>(out) + ((size_t)(q * K + r)) * 16 + h * 8;
        #pragma unroll
        for (int i = 0; i < 8; ++i) {
            const float4 a = vp[i];
            const float4 b = fp[i];
            float4 c;
            c.x = (a.x + b.x) * wgt;
            c.y = (a.y + b.y) * wgt;
            c.z = (a.z + b.z) * wgt;
            c.w = (a.w + b.w) * wgt;
            op[i] = c;
        }
        if (l16 < 8) {
            out[IDX_OFF + (size_t)q * K + l16] = (float)wi[l16];
        } else {
            const int r2 = l16 - 8;
            out[TSO_OFF + (size_t)q * K + r2] = timestamps[wi[r2]];
        }
    }
}

// ---------------- Last-resort fallback (pure fp32, ws < 3MB) ----------------
#define FQPB   32
#define FTPQ   8
#define FBLOCK 256
#define FTS    128
#define FLDK   68
#define FNTILES (NSLOTS / FTS)

__global__ __launch_bounds__(FBLOCK, 2)
void ltm_fused_kernel(const float* __restrict__ queries,
                      const float* __restrict__ keys_mem,
                      const float* __restrict__ vals_mem,
                      const float* __restrict__ fast_vals,
                      const float* __restrict__ timestamps,
                      float* __restrict__ out)
{
    __shared__ float kt[FTS * FLDK];
    __shared__ float candv[FQPB][FTPQ * K];
    __shared__ int   candi[FQPB][FTPQ * K];
    __shared__ float selw[FQPB][K];
    __shared__ int   seli[FQPB][K];

    const int tid = threadIdx.x;
    const int ql  = tid / FTPQ;
    const int sub = tid % FTPQ;
    const int q   = blockIdx.x * FQPB + ql;

    float4 qv[D / 4];
    {
        const float4* qp = reinterpret_cast<const float4*>(queries + (size_t)q * D);
        #pragma unroll
        for (int i = 0; i < D / 4; ++i) qv[i] = qp[i];
    }

    float tv[K]; int ti[K];
    #pragma unroll
    for (int i = 0; i < K; ++i) { tv[i] = -INFINITY; ti[i] = 0; }

    for (int tile = 0; tile < FNTILES; ++tile) {
        __syncthreads();
        {
            const float4* kg = reinterpret_cast<const float4*>(keys_mem + (size_t)tile * FTS * D);
            #pragma unroll
            for (int i = 0; i < (FTS * D / 4) / FBLOCK; ++i) {
                const int e = tid + i * FBLOCK;
                const int row = e >> 4;
                const int col = e & 15;
                *reinterpret_cast<float4*>(&kt[row * FLDK + col * 4]) = kg[e];
            }
        }
        __syncthreads();

        #pragma unroll 4
        for (int j = 0; j < FTS / FTPQ; ++j) {
            const int local = sub + j * FTPQ;
            const float* kr = &kt[local * FLDK];
            float4 a0 = make_float4(0.f, 0.f, 0.f, 0.f);
            float4 a1 = make_float4(0.f, 0.f, 0.f, 0.f);
            #pragma unroll
            for (int i = 0; i < D / 4; i += 2) {
                const float4 k0 = *reinterpret_cast<const float4*>(&kr[(i + 0) * 4]);
                const float4 k1 = *reinterpret_cast<const float4*>(&kr[(i + 1) * 4]);
                a0.x = fmaf(k0.x, qv[i].x, a0.x);   a0.y = fmaf(k0.y, qv[i].y, a0.y);
                a0.z = fmaf(k0.z, qv[i].z, a0.z);   a0.w = fmaf(k0.w, qv[i].w, a0.w);
                a1.x = fmaf(k1.x, qv[i+1].x, a1.x); a1.y = fmaf(k1.y, qv[i+1].y, a1.y);
                a1.z = fmaf(k1.z, qv[i+1].z, a1.z); a1.w = fmaf(k1.w, qv[i+1].w, a1.w);
            }
            float s = ((a0.x + a1.x) + (a0.y + a1.y)) + ((a0.z + a1.z) + (a0.w + a1.w));
            s *= 0.125f;
            const int gid = tile * FTS + local;
            if (s > tv[0]) {
                tv[0] = s; ti[0] = gid;
                #pragma unroll
                for (int u = 0; u < K - 1; ++u) {
                    const bool sw = tv[u] > tv[u + 1];
                    const float va = sw ? tv[u + 1] : tv[u];
                    const float vb = sw ? tv[u]     : tv[u + 1];
                    const int   ia = sw ? ti[u + 1] : ti[u];
                    const int   ib = sw ? ti[u]     : ti[u + 1];
                    tv[u] = va; tv[u + 1] = vb; ti[u] = ia; ti[u + 1] = ib;
                }
            }
        }
    }

    #pragma unroll
    for (int i = 0; i < K; ++i) {
        candv[ql][sub * K + i] = tv[i];
        candi[ql][sub * K + i] = ti[i];
    }
    __syncthreads();

    if (sub == 0) {
        float wv[K]; int wi[K];
        #pragma unroll
        for (int r = 0; r < K; ++r) {
            float bv = -INFINITY; int bi = 0x7fffffff; int bp = 0;
            for (int c = 0; c < FTPQ * K; ++c) {
                const float v = candv[ql][c];
                const int  id = candi[ql][c];
                if ((v > bv) || (v == bv && id < bi)) { bv = v; bi = id; bp = c; }
            }
            candv[ql][bp] = -INFINITY;
            wv[r] = bv; wi[r] = bi;
        }
        const float m = wv[0];
        float e[K]; float sum = 0.f;
        #pragma unroll
        for (int r = 0; r < K; ++r) { e[r] = expf(wv[r] - m); sum += e[r]; }
        const float inv = 1.f / sum;
        #pragma unroll
        for (int r = 0; r < K; ++r) { selw[ql][r] = e[r] * inv; seli[ql][r] = wi[r]; }
    }
    __syncthreads();

    {
        const int r = sub;
        const int id = seli[ql][r];
        const float w = selw[ql][r];
        const float4* vp = reinterpret_cast<const float4*>(vals_mem  + (size_t)id * D);
        const float4* fp = reinterpret_cast<const float4*>(fast_vals + (size_t)id * D);
        float4* op = reinterpret_cast<float4*>(out + (size_t)(q * K + r) * D);
        #pragma unroll
        for (int i = 0; i < D / 4; ++i) {
            const float4 a = vp[i];
            const float4 b = fp[i];
            float4 c;
            c.x = (a.x + b.x) * w; c.y = (a.y + b.y) * w;
            c.z = (a.z + b.z) * w; c.w = (a.w + b.w) * w;
            op[i] = c;
        }
        out[IDX_OFF + (size_t)q * K + r] = (float)id;
        out[TSO_OFF + (size_t)q * K + r] = timestamps[id];
    }
}

extern "C" void kernel_launch(void* const* d_in, const int* in_sizes, int n_in,
                              void* d_out, int out_size, void* d_ws, size_t ws_size,
                              hipStream_t stream) {
    (void)in_sizes; (void)n_in; (void)out_size;
    const float* queries    = (const float*)d_in[0];
    const float* keys_mem   = (const float*)d_in[1];
    const float* vals_mem   = (const float*)d_in[2];
    const float* fast_vals  = (const float*)d_in[3];
    const float* timestamps = (const float*)d_in[4];
    float* out = (float*)d_out;

    if (ws_size >= WS_NEED_NEW) {
        unsigned short* ws = (unsigned short*)d_ws;
        unsigned short* poolu = ws + POOL_SHORT_OFF;
        conv_keys_kernel<<<512, 256, 0, stream>>>(keys_mem, ws);
        ltm_prefilter_kernel<<<(NQ / QPB_P) * HALVES, BLOCK_P, 0, stream>>>(
            ws /*Kb*/, queries, poolu);
        ltm_rescore_kernel<<<NQ / QPB_R, BLOCK_R, 0, stream>>>(
            queries, keys_mem, vals_mem, fast_vals, timestamps, poolu, out);
    } else if (ws_size >= WS_NEED_OLD) {
        unsigned short* ws = (unsigned short*)d_ws;
        conv_kernel<<<1536, 256, 0, stream>>>(queries, keys_mem, ws);
        ltm_mfma_kernel<<<NQ / QPB, BLOCK, 0, stream>>>(
            queries, keys_mem, vals_mem, fast_vals, timestamps,
            ws /*Kb*/, ws + 524288 /*Qb*/, out);
    } else {
        ltm_fused_kernel<<<NQ / FQPB, FBLOCK, 0, stream>>>(
            queries, keys_mem, vals_mem, fast_vals, timestamps, out);
    }
}

// Round 16
// 106.904 us; speedup vs baseline: 1.0994x; 1.0321x over previous
//
#include <hip/hip_runtime.h>
#include <math.h>

// Problem constants (fixed by the reference)
#define NQ      16384      // B*S = 8*2048
#define NSLOTS  8192
#define D       64
#define K       8

#define WV_ELEMS  (NQ * K * D)     // 8,388,608
#define IDX_OFF   (WV_ELEMS)
#define TSO_OFF   (IDX_OFF + NQ * K)

// ---------------- MFMA split path (P = prefilter, R = rescore) ----------------
#define QPB_P   32         // queries per P block
#define BLOCK_P 512        // 8 waves
#define HALVES  2          // slot halves -> grid 1024 -> 4 blocks/CU
#define SPW_P   (NSLOTS / HALVES / 8)   // 512 slots per wave
#define ITERS_P (SPW_P / 32)            // 16

#define QPB_R   8          // queries per R block -> grid 2048 (100% wave capacity)
#define BLOCK_R 256

// ws layout (unsigned short base):
//   [0, 524288)          kb    bf16 keys    [8192][64]
//   [524288, 1572864)    qb    bf16 q*0.125 [16384][64]
//   [1572864, 2097152)   pool  ushort[16384][32] slot ids (16 per half)
#define POOL_SHORT_OFF 1572864
#define WS_NEED_NEW  (4u * 1024u * 1024u)
#define WS_NEED_OLD  (3u * 1024u * 1024u)

using short8   = __attribute__((ext_vector_type(8))) short;
using ushort8  = __attribute__((ext_vector_type(8))) unsigned short;
using bf16x8   = __attribute__((ext_vector_type(8))) __bf16;
using f32x4    = __attribute__((ext_vector_type(4))) float;

#define MFMA_BF16(A, B, C) __builtin_amdgcn_mfma_f32_16x16x32_bf16((A), (B), (C), 0, 0, 0)

__device__ __forceinline__ bf16x8 load_frag(const unsigned short* p) {
    short8 s = *reinterpret_cast<const short8*>(p);
    return __builtin_bit_cast(bf16x8, s);
}

// Pack score into a float key: clear low 13 mantissa bits, OR in (8191 - slot).
__device__ __forceinline__ float packkey(float s, int code) {
    unsigned u = __float_as_uint(s) & 0xFFFFE000u;
    return __uint_as_float(u | (unsigned)code);
}

// Branchless insert into ascending sorted tv[0..7] (tv[0] = current 8th best).
__device__ __forceinline__ void ins8(float (&tv)[8], float key) {
    float k2 = fmaxf(key, tv[0]);
    float o0 = fminf(tv[1], k2);
    float o1 = __builtin_amdgcn_fmed3f(tv[1], tv[2], k2);
    float o2 = __builtin_amdgcn_fmed3f(tv[2], tv[3], k2);
    float o3 = __builtin_amdgcn_fmed3f(tv[3], tv[4], k2);
    float o4 = __builtin_amdgcn_fmed3f(tv[4], tv[5], k2);
    float o5 = __builtin_amdgcn_fmed3f(tv[5], tv[6], k2);
    float o6 = __builtin_amdgcn_fmed3f(tv[6], tv[7], k2);
    float o7 = fmaxf(tv[7], k2);
    tv[0]=o0; tv[1]=o1; tv[2]=o2; tv[3]=o3; tv[4]=o4; tv[5]=o5; tv[6]=o6; tv[7]=o7;
}

__device__ __forceinline__ void cs(float& a, float& b) {
    const float lo = fminf(a, b), hi = fmaxf(a, b);
    a = lo; b = hi;
}
// Sort an 8-element BITONIC sequence ascending (3-stage bitonic merge).
__device__ __forceinline__ void sort_bitonic8(float (&v)[8]) {
    cs(v[0],v[4]); cs(v[1],v[5]); cs(v[2],v[6]); cs(v[3],v[7]);
    cs(v[0],v[2]); cs(v[1],v[3]); cs(v[4],v[6]); cs(v[5],v[7]);
    cs(v[0],v[1]); cs(v[2],v[3]); cs(v[4],v[5]); cs(v[6],v[7]);
}

__device__ __forceinline__ void csu(unsigned long long& a, unsigned long long& b) {
    const bool lt = a < b;
    const unsigned long long lo = lt ? a : b;
    const unsigned long long hi = lt ? b : a;
    a = lo; b = hi;
}
__device__ __forceinline__ void sort_bitonic8_u64(unsigned long long (&v)[8]) {
    csu(v[0],v[4]); csu(v[1],v[5]); csu(v[2],v[6]); csu(v[3],v[7]);
    csu(v[0],v[2]); csu(v[1],v[3]); csu(v[4],v[6]); csu(v[5],v[7]);
    csu(v[0],v[1]); csu(v[2],v[3]); csu(v[4],v[5]); csu(v[6],v[7]);
}

// fp32 -> bf16 round-to-nearest-even (inputs are finite)
__device__ __forceinline__ unsigned short f2bf(float f) {
    unsigned u = __float_as_uint(f);
    return (unsigned short)((u + 0x7FFFu + ((u >> 16) & 1u)) >> 16);
}

__global__ __launch_bounds__(256)
void conv_kernel(const float* __restrict__ q, const float* __restrict__ k,
                 unsigned short* __restrict__ ws) {
    const int t = blockIdx.x * blockDim.x + threadIdx.x;
    if (t < 262144) {                      // queries: 1,048,576 floats = 262,144 float4
        float4 v = reinterpret_cast<const float4*>(q)[t];
        unsigned long long r =
              (unsigned long long)f2bf(v.x * 0.125f)
            | ((unsigned long long)f2bf(v.y * 0.125f) << 16)
            | ((unsigned long long)f2bf(v.z * 0.125f) << 32)
            | ((unsigned long long)f2bf(v.w * 0.125f) << 48);
        reinterpret_cast<unsigned long long*>(ws + 524288)[t] = r;   // Qb at +1MB
    } else if (t < 393216) {               // keys: 524,288 floats = 131,072 float4
        const int i = t - 262144;
        float4 v = reinterpret_cast<const float4*>(k)[i];
        unsigned long long r =
              (unsigned long long)f2bf(v.x)
            | ((unsigned long long)f2bf(v.y) << 16)
            | ((unsigned long long)f2bf(v.z) << 32)
            | ((unsigned long long)f2bf(v.w) << 48);
        reinterpret_cast<unsigned long long*>(ws)[i] = r;            // Kb at 0
    }
}

// ================= Kernel P: bf16 MFMA prefilter -> per-(query,half) top-16 =
// (round-11 version: 2 chains, prefetch + unroll 2, bounds(512,8), VGPR 32)
__global__ __launch_bounds__(BLOCK_P, 8)
void ltm_prefilter_kernel(const unsigned short* __restrict__ kb,
                          const unsigned short* __restrict__ qb,
                          unsigned short* __restrict__ poolu)
{
    __shared__ float candk[QPB_P][68];   // 64 packed keys per query (+pad)

    const int tid  = threadIdx.x;
    const int lane = tid & 63;
    const int w    = tid >> 6;          // wave 0..7
    const int row  = lane & 15;
    const int g    = lane >> 4;         // 0..3
    const int g4   = g * 4;
    const int koff = g * 8;             // k-offset (elements) within 32-chunk
    const int bid  = blockIdx.x;
    const int qbase = (bid >> 1) * QPB_P;
    const int half  = bid & 1;

    // B fragments (queries), hoisted: 2 query subtiles x 2 k-chunks
    const unsigned short* qpA = qb + (size_t)(qbase + row) * D + koff;
    const bf16x8 bA0 = load_frag(qpA);
    const bf16x8 bA1 = load_frag(qpA + 32);
    const bf16x8 bB0 = load_frag(qpA + 16 * D);
    const bf16x8 bB1 = load_frag(qpA + 16 * D + 32);

    float tvA[8], tvB[8];
    #pragma unroll
    for (int i = 0; i < 8; ++i) { tvA[i] = -INFINITY; tvB[i] = -INFINITY; }

    const int wbase = half * (NSLOTS / HALVES) + w * SPW_P;

    // register prefetch (depth 1) + unroll 2
    const unsigned short* kp0 = kb + (size_t)(wbase + row) * D + koff;
    bf16x8 a00 = load_frag(kp0);
    bf16x8 a01 = load_frag(kp0 + 32);
    bf16x8 a10 = load_frag(kp0 + 16 * D);
    bf16x8 a11 = load_frag(kp0 + 16 * D + 32);

    int codeA = 8191 - (wbase + g4);   // complement base; decremented 32/iter

    #pragma unroll 2
    for (int it = 0; it < ITERS_P; ++it) {
        // prefetch next iter's A fragments (last iter reads past this wave's
        // range into kb/qb: valid ws memory, values unused)
        const int snext = wbase + (it + 1) * 32;
        const unsigned short* np_ = kb + (size_t)(snext + row) * D + koff;
        bf16x8 n00 = load_frag(np_);
        bf16x8 n01 = load_frag(np_ + 32);
        bf16x8 n10 = load_frag(np_ + 16 * D);
        bf16x8 n11 = load_frag(np_ + 16 * D + 32);

        const f32x4 z = {0.f, 0.f, 0.f, 0.f};
        f32x4 c00 = MFMA_BF16(a00, bA0, z);  c00 = MFMA_BF16(a01, bA1, c00);
        f32x4 c01 = MFMA_BF16(a00, bB0, z);  c01 = MFMA_BF16(a01, bB1, c01);
        f32x4 c10 = MFMA_BF16(a10, bA0, z);  c10 = MFMA_BF16(a11, bA1, c10);
        f32x4 c11 = MFMA_BF16(a10, bB0, z);  c11 = MFMA_BF16(a11, bB1, c11);

        // slot(tile0, r) = s0 + g4 + r ; slot(tile1, r) = s0 + 16 + g4 + r
        ins8(tvA, packkey(c00[0], codeA     ));
        ins8(tvA, packkey(c00[1], codeA -  1));
        ins8(tvA, packkey(c00[2], codeA -  2));
        ins8(tvA, packkey(c00[3], codeA -  3));
        ins8(tvA, packkey(c10[0], codeA - 16));
        ins8(tvA, packkey(c10[1], codeA - 17));
        ins8(tvA, packkey(c10[2], codeA - 18));
        ins8(tvA, packkey(c10[3], codeA - 19));
        ins8(tvB, packkey(c01[0], codeA     ));
        ins8(tvB, packkey(c01[1], codeA -  1));
        ins8(tvB, packkey(c01[2], codeA -  2));
        ins8(tvB, packkey(c01[3], codeA -  3));
        ins8(tvB, packkey(c11[0], codeA - 16));
        ins8(tvB, packkey(c11[1], codeA - 17));
        ins8(tvB, packkey(c11[2], codeA - 18));
        ins8(tvB, packkey(c11[3], codeA - 19));

        codeA -= 32;
        a00 = n00; a01 = n01; a10 = n10; a11 = n11;
    }

    // ---- In-wave merge to per-wave sorted top-8 per query ----
    {
        float sA[8], sB[8];
        #pragma unroll
        for (int j = 0; j < 8; ++j) {
            sA[j] = __shfl_xor(tvA[j], 32, 64);
            sB[j] = __shfl_xor(tvB[j], 32, 64);
        }
        float mA[8], mB[8];
        #pragma unroll
        for (int j = 0; j < 8; ++j) {
            mA[j] = fmaxf(tvA[j], sA[7 - j]);
            mB[j] = fmaxf(tvB[j], sB[7 - j]);
        }
        sort_bitonic8(mA);
        sort_bitonic8(mB);
        #pragma unroll
        for (int j = 0; j < 8; ++j) {
            sA[j] = __shfl_xor(mA[j], 16, 64);
            sB[j] = __shfl_xor(mB[j], 16, 64);
        }
        float fA[8], fB[8];
        #pragma unroll
        for (int j = 0; j < 8; ++j) {
            fA[j] = fmaxf(mA[j], sA[7 - j]);
            fB[j] = fmaxf(mB[j], sB[7 - j]);
        }
        sort_bitonic8(fA);
        sort_bitonic8(fB);
        if (g == 0) {
            #pragma unroll
            for (int j = 0; j < 8; ++j) {
                candk[row     ][w * 8 + j] = fA[j];
                candk[row + 16][w * 8 + j] = fB[j];
            }
        }
    }
    __syncthreads();

    // ---- Block merge: 8 sorted-8 lists -> per-(query,half) sorted TOP-16.
    // 8 threads/query. Round 1 (xor 1): Batcher half-cleaner -> pair holds
    // sorted-16 (even thread = low 8, odd = high 8). Rounds 2,3 (xor 3, xor 5):
    // top-16 of two distributed sorted-16s = max(A16[i], B16[15-i]) (bitonic),
    // then cross-pair half-clean (xor 1) + local bitonic sort.
    if (tid < 256) {
        const int  ql = tid >> 3;    // 0..31
        const int  jj = tid & 7;     // 0..7
        const bool hi = (jj & 1) != 0;

        float v[8];
        #pragma unroll
        for (int i = 0; i < 8; ++i) v[i] = candk[ql][jj * 8 + i];

        // Round 1
        {
            float sk[8], mk[8];
            #pragma unroll
            for (int i = 0; i < 8; ++i) sk[i] = __shfl_xor(v[i], 1, 64);
            #pragma unroll
            for (int i = 0; i < 8; ++i)
                mk[i] = hi ? fmaxf(v[i], sk[7 - i]) : fminf(v[i], sk[7 - i]);
            sort_bitonic8(mk);
            #pragma unroll
            for (int i = 0; i < 8; ++i) v[i] = mk[i];
        }
        // Rounds 2 and 3
        #pragma unroll
        for (int rnd = 0; rnd < 2; ++rnd) {
            const int st = rnd ? 5 : 3;
            float sk[8], mk[8], sk2[8];
            #pragma unroll
            for (int i = 0; i < 8; ++i) sk[i] = __shfl_xor(v[i], st, 64);
            #pragma unroll
            for (int i = 0; i < 8; ++i) mk[i] = fmaxf(v[i], sk[7 - i]);
            #pragma unroll
            for (int i = 0; i < 8; ++i) sk2[i] = __shfl_xor(mk[i], 1, 64);
            #pragma unroll
            for (int i = 0; i < 8; ++i)
                mk[i] = hi ? fmaxf(mk[i], sk2[i]) : fminf(mk[i], sk2[i]);
            sort_bitonic8(mk);
            #pragma unroll
            for (int i = 0; i < 8; ++i) v[i] = mk[i];
        }
        // Threads 0,1 hold the half's sorted top-16; write slot ids (ushort).
        if (jj < 2) {
            ushort8 o;
            #pragma unroll
            for (int i = 0; i < 8; ++i)
                o[i] = (unsigned short)(8191u - (__float_as_uint(v[i]) & 8191u));
            *reinterpret_cast<ushort8*>(
                poolu + ((size_t)(qbase + ql) * 32 + half * 16 + jj * 8)) = o;
        }
    }
}

// ================= Kernel R: exact fp32 rescore of 32 candidates/query =======
// 32 lanes per query (grid 2048 -> 8192 waves = 100% of chip wave capacity).
// Each 4-lane subgroup owns 4 candidates; sorted-4 is zero-padded into a
// depth-8 list, then 3 Batcher merge rounds (strides 4, 8, 16) produce the
// exact top-8 of all 32 on every lane.
__global__ __launch_bounds__(BLOCK_R, 8)
void ltm_rescore_kernel(const float* __restrict__ queries,
                        const float* __restrict__ keys_mem,
                        const float* __restrict__ vals_mem,
                        const float* __restrict__ fast_vals,
                        const float* __restrict__ timestamps,
                        const unsigned short* __restrict__ poolu,
                        float* __restrict__ out)
{
    const int tid = threadIdx.x;
    const int ql  = tid >> 5;    // 0..7
    const int l32 = tid & 31;
    const int sg  = l32 >> 2;    // 0..7
    const int ls4 = l32 & 3;     // 0..3
    const int q   = blockIdx.x * QPB_R + ql;

    float4 qv4[4];
    {
        const float4* qp = reinterpret_cast<const float4*>(queries) + (size_t)q * 16 + ls4 * 4;
        #pragma unroll
        for (int i = 0; i < 4; ++i) qv4[i] = qp[i];
    }

    unsigned long long kk[4];
    #pragma unroll
    for (int jt = 0; jt < 4; ++jt) {
        const int sid = poolu[(size_t)q * 32 + sg * 4 + jt];    // broadcast load
        const float4* kp = reinterpret_cast<const float4*>(keys_mem) + (size_t)sid * 16 + ls4 * 4;
        float p = 0.f;
        #pragma unroll
        for (int i = 0; i < 4; ++i) {
            const float4 kc = kp[i];
            p = fmaf(qv4[i].x, kc.x, p);
            p = fmaf(qv4[i].y, kc.y, p);
            p = fmaf(qv4[i].z, kc.z, p);
            p = fmaf(qv4[i].w, kc.w, p);
        }
        p += __shfl_xor(p, 1, 64);
        p += __shfl_xor(p, 2, 64);
        const float s = p * 0.125f;
        // exact total-order key: (orderable(score) << 13) | (8191 - sid)
        const unsigned u  = __float_as_uint(s);
        const unsigned ou = (u & 0x80000000u) ? ~u : (u | 0x80000000u);
        kk[jt] = ((unsigned long long)ou << 13) | (unsigned)(8191 - sid);
    }
    // sort-4 (5 comparators), then zero-pad into ascending depth-8 list
    csu(kk[0], kk[1]); csu(kk[2], kk[3]);
    csu(kk[0], kk[2]); csu(kk[1], kk[3]);
    csu(kk[1], kk[2]);
    unsigned long long tk[8];
    tk[0] = 0ull; tk[1] = 0ull; tk[2] = 0ull; tk[3] = 0ull;
    tk[4] = kk[0]; tk[5] = kk[1]; tk[6] = kk[2]; tk[7] = kk[3];

    // Cross-subgroup merge: strides 4, 8, 16 (Batcher upper-half + bitonic sort).
    #pragma unroll
    for (int st = 4; st <= 16; st <<= 1) {
        unsigned long long sk[8], mk[8];
        #pragma unroll
        for (int j = 0; j < 8; ++j) sk[j] = __shfl_xor(tk[j], st, 64);
        #pragma unroll
        for (int j = 0; j < 8; ++j) {
            const unsigned long long a = tk[j], b = sk[7 - j];
            mk[j] = a > b ? a : b;
        }
        sort_bitonic8_u64(mk);
        #pragma unroll
        for (int j = 0; j < 8; ++j) tk[j] = mk[j];
    }

    // ---- decode + softmax (redundant per lane, no sync needed) ----
    float wv[K]; int wi[K];
    #pragma unroll
    for (int r = 0; r < K; ++r) {
        const unsigned long long best = tk[7 - r];
        const int      sid = 8191 - (int)(best & 8191ull);
        const unsigned ou  = (unsigned)(best >> 13);
        const unsigned ub  = (ou & 0x80000000u) ? (ou & 0x7FFFFFFFu) : ~ou;
        wv[r] = __uint_as_float(ub);
        wi[r] = sid;
    }
    const float m = wv[0];
    float e[K]; float sum = 0.f;
    #pragma unroll
    for (int r = 0; r < K; ++r) { e[r] = expf(wv[r] - m); sum += e[r]; }
    const float inv = 1.f / sum;

    // ---- epilogue — lane (r, s4) = (l32>>2, l32&3) owns 64 B of rank r ----
    {
        const int   r   = l32 >> 2;
        const int   s4  = l32 & 3;
        const int   id  = wi[r];
        const float wgt = e[r] * inv;
        const float4* vp = reinterpret_cast<const float4*>(vals_mem)  + (size_t)id * 16 + s4 * 4;
        const float4* fp = reinterpret_cast<const float4*>(fast_vals) + (size_t)id * 16 + s4 * 4;
        float4* op = reinterpret_cast<float4*>(out) + ((size_t)(q * K + r)) * 16 + s4 * 4;
        #pragma unroll
        for (int i = 0; i < 4; ++i) {
            const float4 a = vp[i];
            const float4 b = fp[i];
            float4 c;
            c.x = (a.x + b.x) * wgt;
            c.y = (a.y + b.y) * wgt;
            c.z = (a.z + b.z) * wgt;
            c.w = (a.w + b.w) * wgt;
            op[i] = c;
        }
        if (l32 < 8) {
            out[IDX_OFF + (size_t)q * K + l32] = (float)wi[l32];
        } else if (l32 < 16) {
            const int r2 = l32 - 8;
            out[TSO_OFF + (size_t)q * K + r2] = timestamps[wi[r2]];
        }
    }
}

// ============ Mid fallback: round-8 single kernel (ws in [3MB,4MB)) =========
#define QPB    32
#define BLOCK  512
#define WAVES  8
#define SPW    (NSLOTS / WAVES)
#define ITERS  (SPW / 32)

__global__ __launch_bounds__(BLOCK, 4)
void ltm_mfma_kernel(const float* __restrict__ queries,
                     const float* __restrict__ keys_mem,
                     const float* __restrict__ vals_mem,
                     const float* __restrict__ fast_vals,
                     const float* __restrict__ timestamps,
                     const unsigned short* __restrict__ kb,
                     const unsigned short* __restrict__ qb,
                     float* __restrict__ out)
{
    __shared__ float candk[QPB][68];

    const int tid  = threadIdx.x;
    const int lane = tid & 63;
    const int w    = tid >> 6;
    const int row  = lane & 15;
    const int g    = lane >> 4;
    const int g4   = g * 4;
    const int koff = g * 8;
    const int qbase = blockIdx.x * QPB;

    const unsigned short* qpA = qb + (size_t)(qbase + row) * D + koff;
    const bf16x8 bA0 = load_frag(qpA);
    const bf16x8 bA1 = load_frag(qpA + 32);
    const bf16x8 bB0 = load_frag(qpA + 16 * D);
    const bf16x8 bB1 = load_frag(qpA + 16 * D + 32);

    float tvA[8], tvB[8];
    #pragma unroll
    for (int i = 0; i < 8; ++i) { tvA[i] = -INFINITY; tvB[i] = -INFINITY; }

    const int wbase = w * SPW;
    const unsigned short* kp0 = kb + (size_t)(wbase + row) * D + koff;
    bf16x8 a00 = load_frag(kp0);
    bf16x8 a01 = load_frag(kp0 + 32);
    bf16x8 a10 = load_frag(kp0 + 16 * D);
    bf16x8 a11 = load_frag(kp0 + 16 * D + 32);

    int codeA = 8191 - (wbase + g4);

    #pragma unroll 2
    for (int it = 0; it < ITERS; ++it) {
        const int snext = wbase + (it + 1) * 32;
        const unsigned short* np_ = kb + (size_t)(snext + row) * D + koff;
        bf16x8 n00 = load_frag(np_);
        bf16x8 n01 = load_frag(np_ + 32);
        bf16x8 n10 = load_frag(np_ + 16 * D);
        bf16x8 n11 = load_frag(np_ + 16 * D + 32);

        const f32x4 z = {0.f, 0.f, 0.f, 0.f};
        f32x4 c00 = MFMA_BF16(a00, bA0, z);  c00 = MFMA_BF16(a01, bA1, c00);
        f32x4 c01 = MFMA_BF16(a00, bB0, z);  c01 = MFMA_BF16(a01, bB1, c01);
        f32x4 c10 = MFMA_BF16(a10, bA0, z);  c10 = MFMA_BF16(a11, bA1, c10);
        f32x4 c11 = MFMA_BF16(a10, bB0, z);  c11 = MFMA_BF16(a11, bB1, c11);

        ins8(tvA, packkey(c00[0], codeA     ));
        ins8(tvA, packkey(c00[1], codeA -  1));
        ins8(tvA, packkey(c00[2], codeA -  2));
        ins8(tvA, packkey(c00[3], codeA -  3));
        ins8(tvA, packkey(c10[0], codeA - 16));
        ins8(tvA, packkey(c10[1], codeA - 17));
        ins8(tvA, packkey(c10[2], codeA - 18));
        ins8(tvA, packkey(c10[3], codeA - 19));
        ins8(tvB, packkey(c01[0], codeA     ));
        ins8(tvB, packkey(c01[1], codeA -  1));
        ins8(tvB, packkey(c01[2], codeA -  2));
        ins8(tvB, packkey(c01[3], codeA -  3));
        ins8(tvB, packkey(c11[0], codeA - 16));
        ins8(tvB, packkey(c11[1], codeA - 17));
        ins8(tvB, packkey(c11[2], codeA - 18));
        ins8(tvB, packkey(c11[3], codeA - 19));

        codeA -= 32;
        a00 = n00; a01 = n01; a10 = n10; a11 = n11;
    }

    {
        float sA[8], sB[8];
        #pragma unroll
        for (int j = 0; j < 8; ++j) {
            sA[j] = __shfl_xor(tvA[j], 32, 64);
            sB[j] = __shfl_xor(tvB[j], 32, 64);
        }
        float mA[8], mB[8];
        #pragma unroll
        for (int j = 0; j < 8; ++j) {
            mA[j] = fmaxf(tvA[j], sA[7 - j]);
            mB[j] = fmaxf(tvB[j], sB[7 - j]);
        }
        sort_bitonic8(mA);
        sort_bitonic8(mB);
        #pragma unroll
        for (int j = 0; j < 8; ++j) {
            sA[j] = __shfl_xor(mA[j], 16, 64);
            sB[j] = __shfl_xor(mB[j], 16, 64);
        }
        if (g == 0) {
            #pragma unroll
            for (int j = 0; j < 8; ++j) {
                candk[row     ][w * 8 + j] = fmaxf(mA[j], sA[7 - j]);
                candk[row + 16][w * 8 + j] = fmaxf(mB[j], sB[7 - j]);
            }
        }
    }
    __syncthreads();

    const int ql  = tid >> 4;
    const int l16 = tid & 15;
    const int sg  = l16 >> 2;
    const int ls4 = l16 & 3;
    const int q   = qbase + ql;

    float4 qv4[4];
    {
        const float4* qp = reinterpret_cast<const float4*>(queries) + (size_t)q * 16 + ls4 * 4;
        #pragma unroll
        for (int i = 0; i < 4; ++i) qv4[i] = qp[i];
    }

    unsigned long long tk[8];
    #pragma unroll
    for (int i = 0; i < 8; ++i) tk[i] = 0ull;

    #pragma unroll 4
    for (int jt = 0; jt < 16; ++jt) {
        const float fk  = candk[ql][sg * 16 + jt];
        const int   sid = 8191 - (int)(__float_as_uint(fk) & 8191u);
        const float4* kp = reinterpret_cast<const float4*>(keys_mem) + (size_t)sid * 16 + ls4 * 4;
        float p = 0.f;
        #pragma unroll
        for (int i = 0; i < 4; ++i) {
            const float4 kc = kp[i];
            p = fmaf(qv4[i].x, kc.x, p);
            p = fmaf(qv4[i].y, kc.y, p);
            p = fmaf(qv4[i].z, kc.z, p);
            p = fmaf(qv4[i].w, kc.w, p);
        }
        p += __shfl_xor(p, 1, 64);
        p += __shfl_xor(p, 2, 64);
        const float s = p * 0.125f;
        const unsigned u  = __float_as_uint(s);
        const unsigned ou = (u & 0x80000000u) ? ~u : (u | 0x80000000u);
        const unsigned long long key =
            ((unsigned long long)ou << 13) | (unsigned)(8191 - sid);
        if (key > tk[0]) {
            tk[0] = key;
            #pragma unroll
            for (int uu = 0; uu < 7; ++uu) {
                const bool sw = tk[uu] > tk[uu + 1];
                const unsigned long long x = sw ? tk[uu + 1] : tk[uu];
                const unsigned long long y = sw ? tk[uu]     : tk[uu + 1];
                tk[uu] = x; tk[uu + 1] = y;
            }
        }
    }

    #pragma unroll
    for (int st = 4; st <= 8; st <<= 1) {
        unsigned long long sk[8], mk[8];
        #pragma unroll
        for (int j = 0; j < 8; ++j) sk[j] = __shfl_xor(tk[j], st, 64);
        #pragma unroll
        for (int j = 0; j < 8; ++j) {
            const unsigned long long a = tk[j], b = sk[7 - j];
            mk[j] = a > b ? a : b;
        }
        sort_bitonic8_u64(mk);
        #pragma unroll
        for (int j = 0; j < 8; ++j) tk[j] = mk[j];
    }

    float wv[K]; int wi[K];
    #pragma unroll
    for (int r = 0; r < K; ++r) {
        const unsigned long long best = tk[7 - r];
        const int      sid = 8191 - (int)(best & 8191ull);
        const unsigned ou  = (unsigned)(best >> 13);
        const unsigned ub  = (ou & 0x80000000u) ? (ou & 0x7FFFFFFFu) : ~ou;
        wv[r] = __uint_as_float(ub);
        wi[r] = sid;
    }
    const float m = wv[0];
    float e[K]; float sum = 0.f;
    #pragma unroll
    for (int r = 0; r < K; ++r) { e[r] = expf(wv[r] - m); sum += e[r]; }
    const float inv = 1.f / sum;

    {
        const int   r   = l16 >> 1;
        const int   h   = l16 & 1;
        const int   id  = wi[r];
        const float wgt = e[r] * inv;
        const float4* vp = reinterpret_cast<const float4*>(vals_mem)  + (size_t)id * 16 + h * 8;
        const float4* fp = reinterpret_cast<const float4*>(fast_vals) + (size_t)id * 16 + h * 8;
        float4* op = reinterpret_cast<float4*>(out) + ((size_t)(q * K + r)) * 16 + h * 8;
        #pragma unroll
        for (int i = 0; i < 8; ++i) {
            const float4 a = vp[i];
            const float4 b = fp[i];
            float4 c;
            c.x = (a.x + b.x) * wgt;
            c.y = (a.y + b.y) * wgt;
            c.z = (a.z + b.z) * wgt;
            c.w = (a.w + b.w) * wgt;
            op[i] = c;
        }
        if (l16 < 8) {
            out[IDX_OFF + (size_t)q * K + l16] = (float)wi[l16];
        } else {
            const int r2 = l16 - 8;
            out[TSO_OFF + (size_t)q * K + r2] = timestamps[wi[r2]];
        }
    }
}

// ---------------- Last-resort fallback (pure fp32, ws < 3MB) ----------------
#define FQPB   32
#define FTPQ   8
#define FBLOCK 256
#define FTS    128
#define FLDK   68
#define FNTILES (NSLOTS / FTS)

__global__ __launch_bounds__(FBLOCK, 2)
void ltm_fused_kernel(const float* __restrict__ queries,
                      const float* __restrict__ keys_mem,
                      const float* __restrict__ vals_mem,
                      const float* __restrict__ fast_vals,
                      const float* __restrict__ timestamps,
                      float* __restrict__ out)
{
    __shared__ float kt[FTS * FLDK];
    __shared__ float candv[FQPB][FTPQ * K];
    __shared__ int   candi[FQPB][FTPQ * K];
    __shared__ float selw[FQPB][K];
    __shared__ int   seli[FQPB][K];

    const int tid = threadIdx.x;
    const int ql  = tid / FTPQ;
    const int sub = tid % FTPQ;
    const int q   = blockIdx.x * FQPB + ql;

    float4 qv[D / 4];
    {
        const float4* qp = reinterpret_cast<const float4*>(queries + (size_t)q * D);
        #pragma unroll
        for (int i = 0; i < D / 4; ++i) qv[i] = qp[i];
    }

    float tv[K]; int ti[K];
    #pragma unroll
    for (int i = 0; i < K; ++i) { tv[i] = -INFINITY; ti[i] = 0; }

    for (int tile = 0; tile < FNTILES; ++tile) {
        __syncthreads();
        {
            const float4* kg = reinterpret_cast<const float4*>(keys_mem + (size_t)tile * FTS * D);
            #pragma unroll
            for (int i = 0; i < (FTS * D / 4) / FBLOCK; ++i) {
                const int e = tid + i * FBLOCK;
                const int row = e >> 4;
                const int col = e & 15;
                *reinterpret_cast<float4*>(&kt[row * FLDK + col * 4]) = kg[e];
            }
        }
        __syncthreads();

        #pragma unroll 4
        for (int j = 0; j < FTS / FTPQ; ++j) {
            const int local = sub + j * FTPQ;
            const float* kr = &kt[local * FLDK];
            float4 a0 = make_float4(0.f, 0.f, 0.f, 0.f);
            float4 a1 = make_float4(0.f, 0.f, 0.f, 0.f);
            #pragma unroll
            for (int i = 0; i < D / 4; i += 2) {
                const float4 k0 = *reinterpret_cast<const float4*>(&kr[(i + 0) * 4]);
                const float4 k1 = *reinterpret_cast<const float4*>(&kr[(i + 1) * 4]);
                a0.x = fmaf(k0.x, qv[i].x, a0.x);   a0.y = fmaf(k0.y, qv[i].y, a0.y);
                a0.z = fmaf(k0.z, qv[i].z, a0.z);   a0.w = fmaf(k0.w, qv[i].w, a0.w);
                a1.x = fmaf(k1.x, qv[i+1].x, a1.x); a1.y = fmaf(k1.y, qv[i+1].y, a1.y);
                a1.z = fmaf(k1.z, qv[i+1].z, a1.z); a1.w = fmaf(k1.w, qv[i+1].w, a1.w);
            }
            float s = ((a0.x + a1.x) + (a0.y + a1.y)) + ((a0.z + a1.z) + (a0.w + a1.w));
            s *= 0.125f;
            const int gid = tile * FTS + local;
            if (s > tv[0]) {
                tv[0] = s; ti[0] = gid;
                #pragma unroll
                for (int u = 0; u < K - 1; ++u) {
                    const bool sw = tv[u] > tv[u + 1];
                    const float va = sw ? tv[u + 1] : tv[u];
                    const float vb = sw ? tv[u]     : tv[u + 1];
                    const int   ia = sw ? ti[u + 1] : ti[u];
                    const int   ib = sw ? ti[u]     : ti[u + 1];
                    tv[u] = va; tv[u + 1] = vb; ti[u] = ia; ti[u + 1] = ib;
                }
            }
        }
    }

    #pragma unroll
    for (int i = 0; i < K; ++i) {
        candv[ql][sub * K + i] = tv[i];
        candi[ql][sub * K + i] = ti[i];
    }
    __syncthreads();

    if (sub == 0) {
        float wv[K]; int wi[K];
        #pragma unroll
        for (int r = 0; r < K; ++r) {
            float bv = -INFINITY; int bi = 0x7fffffff; int bp = 0;
            for (int c = 0; c < FTPQ * K; ++c) {
                const float v = candv[ql][c];
                const int  id = candi[ql][c];
                if ((v > bv) || (v == bv && id < bi)) { bv = v; bi = id; bp = c; }
            }
            candv[ql][bp] = -INFINITY;
            wv[r] = bv; wi[r] = bi;
        }
        const float m = wv[0];
        float e[K]; float sum = 0.f;
        #pragma unroll
        for (int r = 0; r < K; ++r) { e[r] = expf(wv[r] - m); sum += e[r]; }
        const float inv = 1.f / sum;
        #pragma unroll
        for (int r = 0; r < K; ++r) { selw[ql][r] = e[r] * inv; seli[ql][r] = wi[r]; }
    }
    __syncthreads();

    {
        const int r = sub;
        const int id = seli[ql][r];
        const float w = selw[ql][r];
        const float4* vp = reinterpret_cast<const float4*>(vals_mem  + (size_t)id * D);
        const float4* fp = reinterpret_cast<const float4*>(fast_vals + (size_t)id * D);
        float4* op = reinterpret_cast<float4*>(out + (size_t)(q * K + r) * D);
        #pragma unroll
        for (int i = 0; i < D / 4; ++i) {
            const float4 a = vp[i];
            const float4 b = fp[i];
            float4 c;
            c.x = (a.x + b.x) * w; c.y = (a.y + b.y) * w;
            c.z = (a.z + b.z) * w; c.w = (a.w + b.w) * w;
            op[i] = c;
        }
        out[IDX_OFF + (size_t)q * K + r] = (float)id;
        out[TSO_OFF + (size_t)q * K + r] = timestamps[id];
    }
}

extern "C" void kernel_launch(void* const* d_in, const int* in_sizes, int n_in,
                              void* d_out, int out_size, void* d_ws, size_t ws_size,
                              hipStream_t stream) {
    (void)in_sizes; (void)n_in; (void)out_size;
    const float* queries    = (const float*)d_in[0];
    const float* keys_mem   = (const float*)d_in[1];
    const float* vals_mem   = (const float*)d_in[2];
    const float* fast_vals  = (const float*)d_in[3];
    const float* timestamps = (const float*)d_in[4];
    float* out = (float*)d_out;

    if (ws_size >= WS_NEED_NEW) {
        unsigned short* ws = (unsigned short*)d_ws;
        unsigned short* poolu = ws + POOL_SHORT_OFF;
        conv_kernel<<<1536, 256, 0, stream>>>(queries, keys_mem, ws);
        ltm_prefilter_kernel<<<(NQ / QPB_P) * HALVES, BLOCK_P, 0, stream>>>(
            ws /*Kb*/, ws + 524288 /*Qb*/, poolu);
        ltm_rescore_kernel<<<NQ / QPB_R, BLOCK_R, 0, stream>>>(
            queries, keys_mem, vals_mem, fast_vals, timestamps, poolu, out);
    } else if (ws_size >= WS_NEED_OLD) {
        unsigned short* ws = (unsigned short*)d_ws;
        conv_kernel<<<1536, 256, 0, stream>>>(queries, keys_mem, ws);
        ltm_mfma_kernel<<<NQ / QPB, BLOCK, 0, stream>>>(
            queries, keys_mem, vals_mem, fast_vals, timestamps,
            ws /*Kb*/, ws + 524288 /*Qb*/, out);
    } else {
        ltm_fused_kernel<<<NQ / FQPB, FBLOCK, 0, stream>>>(
            queries, keys_mem, vals_mem, fast_vals, timestamps, out);
    }
}